// Round 1
// baseline (681.934 us; speedup 1.0000x reference)
//
#include <hip/hip_runtime.h>

// ---------- types ----------
typedef short  s16x8 __attribute__((ext_vector_type(8)));
typedef __bf16 bf16x8 __attribute__((ext_vector_type(8)));
typedef float  fx4   __attribute__((ext_vector_type(4)));
typedef unsigned short u16x4 __attribute__((ext_vector_type(4)));

__device__ __forceinline__ fx4 mfma_bf16(s16x8 a, s16x8 b, fx4 c) {
  return __builtin_amdgcn_mfma_f32_16x16x32_bf16(
      __builtin_bit_cast(bf16x8, a), __builtin_bit_cast(bf16x8, b), c, 0, 0, 0);
}

__device__ __forceinline__ unsigned short f2bf(float f) {
  unsigned int u = __float_as_uint(f);
  u += 0x7fffu + ((u >> 16) & 1u);   // RNE
  return (unsigned short)(u >> 16);
}

__device__ __forceinline__ float bf2f(unsigned int bits16) {
  return __uint_as_float(bits16 << 16);
}

// global -> LDS direct copy, 16B per lane; LDS dest = wave-uniform base + lane*16
__device__ __forceinline__ void glds16(const void* g, void* l) {
  __builtin_amdgcn_global_load_lds(
      (__attribute__((address_space(1))) unsigned int*)g,
      (__attribute__((address_space(3))) unsigned int*)l, 16, 0, 0);
}

// ---------- fp32 -> bf16 conversion ----------
__global__ __launch_bounds__(256) void cvt_kernel(const float* __restrict__ src,
                                                  unsigned short* __restrict__ dst, int n) {
  int nv = n >> 2;
  for (int i = blockIdx.x * blockDim.x + threadIdx.x; i < nv; i += gridDim.x * blockDim.x) {
    fx4 v = ((const fx4*)src)[i];
    u16x4 o;
#pragma unroll
    for (int j = 0; j < 4; ++j) o[j] = f2bf(v[j]);
    ((u16x4*)dst)[i] = o;
  }
}

// ---------- per-head RMSNorm (in place, bf16), wave per (row,head) ----------
__global__ __launch_bounds__(256) void rms_kernel(unsigned short* __restrict__ X,
                                                  const float* __restrict__ g,
                                                  float postscale) {
  int unit = blockIdx.x * 4 + (threadIdx.x >> 6);  // (row*16+head), contiguous 128 elems
  int lane = threadIdx.x & 63;
  unsigned short* p = X + (size_t)unit * 128 + lane * 2;
  unsigned int v = *(const unsigned int*)p;
  float a = bf2f(v & 0xffffu);
  float b = bf2f(v >> 16);
  float ss = a * a + b * b;
#pragma unroll
  for (int m = 32; m >= 1; m >>= 1) ss += __shfl_xor(ss, m, 64);
  float rinv = rsqrtf(ss * (1.0f / 128.0f) + 1e-5f) * postscale;
  float ga = g[lane * 2], gb = g[lane * 2 + 1];
  unsigned int out = (unsigned int)f2bf(a * rinv * ga) |
                     ((unsigned int)f2bf(b * rinv * gb) << 16);
  *(unsigned int*)p = out;
}

// ---------- GEMM: C[M,N] = A[M,K] * B[N,K]^T  (m97 structure: 128x128 tile, BK=32) ----------
template <bool BF16OUT>
__global__ __launch_bounds__(256, 2) void gemm_bt(const unsigned short* __restrict__ A,
                                                  const unsigned short* __restrict__ B,
                                                  void* __restrict__ Cv,
                                                  int M, int N, int K) {
  __shared__ unsigned short lA[128 * 32];
  __shared__ unsigned short lB[128 * 32];
  const int tid = threadIdx.x, w = tid >> 6, lane = tid & 63;
  const int lid = lane & 15, grp = lane >> 4;
  const int wr = w >> 1, wc = w & 1;
  const int tm = blockIdx.y * 128, tn = blockIdx.x * 128;

  fx4 acc[4][4];
#pragma unroll
  for (int i = 0; i < 4; ++i)
#pragma unroll
    for (int j = 0; j < 4; ++j) acc[i][j] = fx4{0.f, 0.f, 0.f, 0.f};

  for (int k0 = 0; k0 < K; k0 += 32) {
    __syncthreads();
#pragma unroll
    for (int i = 0; i < 2; ++i) {
      int c = (w * 2 + i) * 64 + lane;       // 16B chunk id, 512 per tile
      int row = c >> 2, u = c & 3;           // tile row, 16B unit in row (32 elems = 4 units)
      glds16(A + (size_t)(tm + row) * K + k0 + u * 8, &lA[(w * 2 + i) * 512]);
      glds16(B + (size_t)(tn + row) * K + k0 + u * 8, &lB[(w * 2 + i) * 512]);
    }
    __syncthreads();
    s16x8 af[4], bf[4];
#pragma unroll
    for (int mi = 0; mi < 4; ++mi)
      af[mi] = *(const s16x8*)&lA[(wr * 64 + mi * 16 + lid) * 32 + grp * 8];
#pragma unroll
    for (int ni = 0; ni < 4; ++ni)
      bf[ni] = *(const s16x8*)&lB[(wc * 64 + ni * 16 + lid) * 32 + grp * 8];
#pragma unroll
    for (int mi = 0; mi < 4; ++mi)
#pragma unroll
      for (int ni = 0; ni < 4; ++ni)
        acc[mi][ni] = mfma_bf16(af[mi], bf[ni], acc[mi][ni]);
  }

#pragma unroll
  for (int mi = 0; mi < 4; ++mi)
#pragma unroll
    for (int ni = 0; ni < 4; ++ni) {
      const int row = tm + wr * 64 + mi * 16 + grp * 4;
      const int col = tn + wc * 64 + ni * 16 + lid;
#pragma unroll
      for (int j = 0; j < 4; ++j) {
        if constexpr (BF16OUT)
          ((unsigned short*)Cv)[(size_t)(row + j) * N + col] = f2bf(acc[mi][ni][j]);
        else
          ((float*)Cv)[(size_t)(row + j) * N + col] = acc[mi][ni][j];
      }
    }
}

// ---------- causal flash attention ----------
// Q,K,V,O: [B*T][2048] bf16, head h occupies cols h*128..h*128+127.
// Block: 64 q-rows (4 waves x 16), one (b,h). KB=32 K/V columns per step.
// Swapped MFMAs: S^T = mfma(K,Q), O^T = mfma(V^T, P^T)  -> per-lane scalar softmax state.
__global__ __launch_bounds__(256, 2) void attn_kernel(const unsigned short* __restrict__ Q,
                                                      const unsigned short* __restrict__ Kt,
                                                      const unsigned short* __restrict__ V,
                                                      unsigned short* __restrict__ O) {
  const int D = 2048, HD = 128, T = 2048;
  __shared__ unsigned short lK[32 * 128];    // XOR-swizzled (16B units within a 256B row)
  __shared__ unsigned short lVT[128 * 40];   // V^T, padded stride 40 elems (80B)

  const int tid = threadIdx.x, w = tid >> 6, lane = tid & 63;
  const int lid = lane & 15, grp = lane >> 4;
  const int qb = blockIdx.x * 64;
  const int b = blockIdx.y >> 4, h = blockIdx.y & 15;
  const size_t base = (size_t)b * T * D + (size_t)h * HD;
  const unsigned short* Qp = Q + base;
  const unsigned short* Kp = Kt + base;
  const unsigned short* Vp = V + base;
  const int q0 = qb + w * 16;
  const int qi = q0 + lid;

  // hoist Q fragments (already RMS-normed and pre-scaled by 128^-0.5)
  s16x8 qf[4];
  {
    const unsigned short* qrow = Qp + (size_t)(q0 + lid) * D;
#pragma unroll
    for (int dc = 0; dc < 4; ++dc) qf[dc] = *(const s16x8*)(qrow + dc * 32 + grp * 8);
  }

  fx4 o[8];
#pragma unroll
  for (int i = 0; i < 8; ++i) o[i] = fx4{0.f, 0.f, 0.f, 0.f};
  float mrun = -1e30f, lrun = 0.f;

  const int nsteps = (qb >> 5) + 2;     // covers k in [0, qb+64)
  for (int s = 0; s < nsteps; ++s) {
    const int kt0 = s << 5;
    __syncthreads();                    // prev-iter LDS reads done
    // stage K tile [32][128]: linear LDS dest, inverse-swizzled global source
#pragma unroll
    for (int i = 0; i < 2; ++i) {
      int c = (w * 2 + i) * 64 + lane;  // 16B chunk, 512 per tile
      int row = c >> 4, u = c & 15;     // row = 256B = 16 units
      int su = u ^ (row & 7);
      glds16(Kp + (size_t)(kt0 + row) * D + su * 8, &lK[(w * 2 + i) * 512]);
    }
    // stage V^T [128d][32kk] (reg-staged, pair-packed writes)
    {
      int kk = (tid & 15) * 2, d0 = (tid >> 4) * 8;
      const unsigned short* vp = Vp + (size_t)(kt0 + kk) * D + d0;
      s16x8 va = *(const s16x8*)vp;
      s16x8 vb = *(const s16x8*)(vp + D);
#pragma unroll
      for (int j = 0; j < 8; ++j) {
        unsigned int pw = (unsigned int)(unsigned short)va[j] |
                          ((unsigned int)(unsigned short)vb[j] << 16);
        *(unsigned int*)&lVT[(d0 + j) * 40 + kk] = pw;
      }
    }
    __syncthreads();                    // staging complete (vmcnt+lgkmcnt drained)
    if (kt0 > q0 + 15) continue;        // wave fully masked; barrier counts stay aligned

    // S^T[k][q] = mfma(K-frag, Q-frag)
    fx4 st[2];
    st[0] = fx4{0.f, 0.f, 0.f, 0.f};
    st[1] = fx4{0.f, 0.f, 0.f, 0.f};
#pragma unroll
    for (int kt = 0; kt < 2; ++kt)
#pragma unroll
      for (int dc = 0; dc < 4; ++dc) {
        int row = kt * 16 + lid;
        int su = (dc * 4 + grp) ^ (row & 7);
        s16x8 kf = *(const s16x8*)&lK[row * 128 + su * 8];
        st[kt] = mfma_bf16(kf, qf[dc], st[kt]);
      }
    // causal mask: lane holds S[k = kt0 + kt*16 + grp*4 + r][q = qi]
    if (kt0 + 31 > q0) {
#pragma unroll
      for (int kt = 0; kt < 2; ++kt)
#pragma unroll
        for (int r = 0; r < 4; ++r)
          if (kt0 + kt * 16 + grp * 4 + r > qi) st[kt][r] = -1e30f;
    }
    // online softmax (q = lid fixed per lane; reduce over the 4 grp-lanes)
    float pmax = st[0][0];
#pragma unroll
    for (int r = 1; r < 4; ++r) pmax = fmaxf(pmax, st[0][r]);
#pragma unroll
    for (int r = 0; r < 4; ++r) pmax = fmaxf(pmax, st[1][r]);
    pmax = fmaxf(pmax, __shfl_xor(pmax, 16, 64));
    pmax = fmaxf(pmax, __shfl_xor(pmax, 32, 64));
    float mnew = fmaxf(mrun, pmax);
    float alpha = __expf(mrun - mnew);
    mrun = mnew;
    float p[8];
    float lloc = 0.f;
#pragma unroll
    for (int kt = 0; kt < 2; ++kt)
#pragma unroll
      for (int r = 0; r < 4; ++r) {
        float e = __expf(st[kt][r] - mnew);
        p[kt * 4 + r] = e;
        lloc += e;
      }
    lrun = lrun * alpha + lloc;
#pragma unroll
    for (int i = 0; i < 8; ++i) o[i] *= alpha;

    // pack P to bf16 pairs and redistribute to PV B-operand layout
    unsigned int w00 = (unsigned int)f2bf(p[0]) | ((unsigned int)f2bf(p[1]) << 16);
    unsigned int w01 = (unsigned int)f2bf(p[2]) | ((unsigned int)f2bf(p[3]) << 16);
    unsigned int w10 = (unsigned int)f2bf(p[4]) | ((unsigned int)f2bf(p[5]) << 16);
    unsigned int w11 = (unsigned int)f2bf(p[6]) | ((unsigned int)f2bf(p[7]) << 16);
    int selA = (grp & 1) * 32 + lid;
    int selB = selA + 16;
    unsigned int t0a = __shfl(w00, selA, 64), t1a = __shfl(w10, selA, 64);
    unsigned int t0b = __shfl(w01, selA, 64), t1b = __shfl(w11, selA, 64);
    unsigned int t0c = __shfl(w00, selB, 64), t1c = __shfl(w10, selB, 64);
    unsigned int t0d = __shfl(w01, selB, 64), t1d = __shfl(w11, selB, 64);
    bool hi = (lane & 32) != 0;                 // kt' = lane>>5
    union PU { s16x8 v; unsigned int u[4]; } pu;
    pu.u[0] = hi ? t1a : t0a;
    pu.u[1] = hi ? t1b : t0b;
    pu.u[2] = hi ? t1c : t0c;
    pu.u[3] = hi ? t1d : t0d;
    s16x8 pf = pu.v;

    // O^T += mfma(V^T-frag, P^T-frag)
#pragma unroll
    for (int dc = 0; dc < 8; ++dc) {
      s16x8 vf = *(const s16x8*)&lVT[(dc * 16 + lid) * 40 + grp * 8];
      o[dc] = mfma_bf16(vf, pf, o[dc]);
    }
  }

  // epilogue: total l over the 4 grp-lanes, normalize, write O[q][d]
  lrun += __shfl_xor(lrun, 16, 64);
  lrun += __shfl_xor(lrun, 32, 64);
  float inv = 1.f / lrun;
  unsigned short* orow = O + base + (size_t)(q0 + lid) * D;
#pragma unroll
  for (int dc = 0; dc < 8; ++dc) {
    u16x4 ov;
#pragma unroll
    for (int r = 0; r < 4; ++r) ov[r] = f2bf(o[dc][r] * inv);
    *(u16x4*)(orow + dc * 16 + grp * 4) = ov;
  }
}

// ---------- launch ----------
extern "C" void kernel_launch(void* const* d_in, const int* in_sizes, int n_in,
                              void* d_out, int out_size, void* d_ws, size_t ws_size,
                              hipStream_t stream) {
  (void)in_sizes; (void)n_in; (void)out_size; (void)ws_size;
  const float* x  = (const float*)d_in[0];
  const float* Wq = (const float*)d_in[1];
  const float* Wk = (const float*)d_in[2];
  const float* Wv = (const float*)d_in[3];
  const float* Wo = (const float*)d_in[4];
  const float* gq = (const float*)d_in[5];
  const float* gk = (const float*)d_in[6];
  float* out = (float*)d_out;

  // workspace layout (bytes): peak 136 MB
  char* W = (char*)d_ws;
  unsigned short* xb    = (unsigned short*)(W);                       // 32 MB  x bf16 (later reused for attn out)
  unsigned short* wslot = (unsigned short*)(W + (size_t)33554432);    //  8 MB  current weight bf16
  unsigned short* Qb    = (unsigned short*)(W + (size_t)41943040);    // 32 MB
  unsigned short* Kb    = (unsigned short*)(W + (size_t)75497472);    // 32 MB
  unsigned short* Vb    = (unsigned short*)(W + (size_t)109051904);   // 32 MB
  unsigned short* AO    = xb;                                         // attn out reuses x region

  const dim3 gg(16, 64);   // N/128, M/128

  cvt_kernel<<<4096, 256, 0, stream>>>(x, xb, 16777216);

  cvt_kernel<<<4096, 256, 0, stream>>>(Wq, wslot, 4194304);
  gemm_bt<true><<<gg, 256, 0, stream>>>(xb, wslot, Qb, 8192, 2048, 2048);
  cvt_kernel<<<4096, 256, 0, stream>>>(Wk, wslot, 4194304);
  gemm_bt<true><<<gg, 256, 0, stream>>>(xb, wslot, Kb, 8192, 2048, 2048);
  cvt_kernel<<<4096, 256, 0, stream>>>(Wv, wslot, 4194304);
  gemm_bt<true><<<gg, 256, 0, stream>>>(xb, wslot, Vb, 8192, 2048, 2048);

  rms_kernel<<<32768, 256, 0, stream>>>(Qb, gq, 0.08838834764831845f); // fold hd^-0.5 into Q
  rms_kernel<<<32768, 256, 0, stream>>>(Kb, gk, 1.0f);

  attn_kernel<<<dim3(32, 64), 256, 0, stream>>>(Qb, Kb, Vb, AO);

  cvt_kernel<<<4096, 256, 0, stream>>>(Wo, wslot, 4194304);
  gemm_bt<false><<<gg, 256, 0, stream>>>(AO, wslot, out, 8192, 2048, 2048);
}

// Round 2
// 604.744 us; speedup vs baseline: 1.1276x; 1.1276x over previous
//
#include <hip/hip_runtime.h>

// ---------- types ----------
typedef short  s16x8 __attribute__((ext_vector_type(8)));
typedef __bf16 bf16x8 __attribute__((ext_vector_type(8)));
typedef float  fx4   __attribute__((ext_vector_type(4)));
typedef float  fx16  __attribute__((ext_vector_type(16)));
typedef unsigned short u16x4 __attribute__((ext_vector_type(4)));

__device__ __forceinline__ fx4 mfma_bf16(s16x8 a, s16x8 b, fx4 c) {
  return __builtin_amdgcn_mfma_f32_16x16x32_bf16(
      __builtin_bit_cast(bf16x8, a), __builtin_bit_cast(bf16x8, b), c, 0, 0, 0);
}

__device__ __forceinline__ fx16 mfma32(s16x8 a, s16x8 b, fx16 c) {
  return __builtin_amdgcn_mfma_f32_32x32x16_bf16(
      __builtin_bit_cast(bf16x8, a), __builtin_bit_cast(bf16x8, b), c, 0, 0, 0);
}

__device__ __forceinline__ unsigned short f2bf(float f) {
  unsigned int u = __float_as_uint(f);
  u += 0x7fffu + ((u >> 16) & 1u);   // RNE
  return (unsigned short)(u >> 16);
}

__device__ __forceinline__ float bf2f(unsigned int bits16) {
  return __uint_as_float(bits16 << 16);
}

// global -> LDS direct copy, 16B per lane; LDS dest = wave-uniform base + lane*16
__device__ __forceinline__ void glds16(const void* g, void* l) {
  __builtin_amdgcn_global_load_lds(
      (__attribute__((address_space(1))) unsigned int*)g,
      (__attribute__((address_space(3))) unsigned int*)l, 16, 0, 0);
}

// ---------- fp32 -> bf16 conversion ----------
__global__ __launch_bounds__(256) void cvt_kernel(const float* __restrict__ src,
                                                  unsigned short* __restrict__ dst, int n) {
  int nv = n >> 2;
  for (int i = blockIdx.x * blockDim.x + threadIdx.x; i < nv; i += gridDim.x * blockDim.x) {
    fx4 v = ((const fx4*)src)[i];
    u16x4 o;
#pragma unroll
    for (int j = 0; j < 4; ++j) o[j] = f2bf(v[j]);
    ((u16x4*)dst)[i] = o;
  }
}

// ---------- per-head RMSNorm (in place, bf16), wave per (row,head) ----------
__global__ __launch_bounds__(256) void rms_kernel(unsigned short* __restrict__ X,
                                                  const float* __restrict__ g,
                                                  float postscale) {
  int unit = blockIdx.x * 4 + (threadIdx.x >> 6);  // (row*16+head), contiguous 128 elems
  int lane = threadIdx.x & 63;
  unsigned short* p = X + (size_t)unit * 128 + lane * 2;
  unsigned int v = *(const unsigned int*)p;
  float a = bf2f(v & 0xffffu);
  float b = bf2f(v >> 16);
  float ss = a * a + b * b;
#pragma unroll
  for (int m = 32; m >= 1; m >>= 1) ss += __shfl_xor(ss, m, 64);
  float rinv = rsqrtf(ss * (1.0f / 128.0f) + 1e-5f) * postscale;
  float ga = g[lane * 2], gb = g[lane * 2 + 1];
  unsigned int out = (unsigned int)f2bf(a * rinv * ga) |
                     ((unsigned int)f2bf(b * rinv * gb) << 16);
  *(unsigned int*)p = out;
}

// ---------- GEMM: C[M,N] = A[M,K] * B[N,K]^T  (m97 structure: 128x128 tile, BK=32) ----------
template <bool BF16OUT>
__global__ __launch_bounds__(256, 2) void gemm_bt(const unsigned short* __restrict__ A,
                                                  const unsigned short* __restrict__ B,
                                                  void* __restrict__ Cv,
                                                  int M, int N, int K) {
  __shared__ unsigned short lA[128 * 32];
  __shared__ unsigned short lB[128 * 32];
  const int tid = threadIdx.x, w = tid >> 6, lane = tid & 63;
  const int lid = lane & 15, grp = lane >> 4;
  const int wr = w >> 1, wc = w & 1;
  const int tm = blockIdx.y * 128, tn = blockIdx.x * 128;

  fx4 acc[4][4];
#pragma unroll
  for (int i = 0; i < 4; ++i)
#pragma unroll
    for (int j = 0; j < 4; ++j) acc[i][j] = fx4{0.f, 0.f, 0.f, 0.f};

  for (int k0 = 0; k0 < K; k0 += 32) {
    __syncthreads();
#pragma unroll
    for (int i = 0; i < 2; ++i) {
      int c = (w * 2 + i) * 64 + lane;       // 16B chunk id, 512 per tile
      int row = c >> 2, u = c & 3;           // tile row, 16B unit in row (32 elems = 4 units)
      glds16(A + (size_t)(tm + row) * K + k0 + u * 8, &lA[(w * 2 + i) * 512]);
      glds16(B + (size_t)(tn + row) * K + k0 + u * 8, &lB[(w * 2 + i) * 512]);
    }
    __syncthreads();
    s16x8 af[4], bf[4];
#pragma unroll
    for (int mi = 0; mi < 4; ++mi)
      af[mi] = *(const s16x8*)&lA[(wr * 64 + mi * 16 + lid) * 32 + grp * 8];
#pragma unroll
    for (int ni = 0; ni < 4; ++ni)
      bf[ni] = *(const s16x8*)&lB[(wc * 64 + ni * 16 + lid) * 32 + grp * 8];
#pragma unroll
    for (int mi = 0; mi < 4; ++mi)
#pragma unroll
      for (int ni = 0; ni < 4; ++ni)
        acc[mi][ni] = mfma_bf16(af[mi], bf[ni], acc[mi][ni]);
  }

#pragma unroll
  for (int mi = 0; mi < 4; ++mi)
#pragma unroll
    for (int ni = 0; ni < 4; ++ni) {
      const int row = tm + wr * 64 + mi * 16 + grp * 4;
      const int col = tn + wc * 64 + ni * 16 + lid;
#pragma unroll
      for (int j = 0; j < 4; ++j) {
        if constexpr (BF16OUT)
          ((unsigned short*)Cv)[(size_t)(row + j) * N + col] = f2bf(acc[mi][ni][j]);
        else
          ((float*)Cv)[(size_t)(row + j) * N + col] = acc[mi][ni][j];
      }
    }
}

// ---------- causal flash attention (m214-style: 32x32 MFMA, QBLK=32/wave, KVBLK=64) ----------
// Q,K,V,O: [B*T][2048] bf16, head h at cols h*128..+127.
// Block: 4 waves x 32 q-rows = 128 q-rows, one (b,h). Swapped MFMAs:
//   S^T = mfma32(K_frag, Q_frag)   C: col=lane&31=q, row=(r&3)+8(r>>2)+4H = kv (mod 32)
//   O^T = mfma32(V^T_frag, P_frag)
// Q pre-scaled by hd^-0.5 * log2(e); softmax in exp2 domain.
__global__ __launch_bounds__(256, 2) void attn_kernel(const unsigned short* __restrict__ Q,
                                                      const unsigned short* __restrict__ Kg,
                                                      const unsigned short* __restrict__ Vg,
                                                      unsigned short* __restrict__ O) {
  const int D = 2048, T = 2048;
  __shared__ unsigned short lK[64 * 128];   // XOR-swizzled: unit u stores logical unit u^(row&7)
  __shared__ unsigned short lVT[128 * 64];  // V^T, unit u' = u ^ ((d&7)^((d>>3)&7))

  const int tid = threadIdx.x, w = tid >> 6, lane = tid & 63;
  const int lam = lane & 31, H = lane >> 5;
  const int qb = blockIdx.x * 128;
  const int b = blockIdx.y >> 4, h = blockIdx.y & 15;
  const size_t base = (size_t)b * T * D + (size_t)h * 128;
  const unsigned short* Qp = Q + base;
  const unsigned short* Kp = Kg + base;
  const unsigned short* Vp = Vg + base;
  const int q0 = qb + w * 32;
  const int q = q0 + lam;

  // hoist Q fragments: qf[s] = Q[q0+lam][s*16 + H*8 .. +7]
  s16x8 qf[8];
  {
    const unsigned short* qrow = Qp + (size_t)q * D + H * 8;
#pragma unroll
    for (int s = 0; s < 8; ++s) qf[s] = *(const s16x8*)(qrow + s * 16);
  }

  fx16 zf;
#pragma unroll
  for (int i = 0; i < 16; ++i) zf[i] = 0.f;
  fx16 o[4] = {zf, zf, zf, zf};
  float mrun = -1e30f, lrun = 0.f;

  const int nsteps = (qb >> 6) + 2;
  for (int s = 0; s < nsteps; ++s) {
    const int kt0 = s << 6;
    __syncthreads();                 // prev-iter LDS reads done
    // ---- stage K [64][128], 1024 x 16B chunks, pre-swizzled global source
#pragma unroll
    for (int i = 0; i < 4; ++i) {
      int c = i * 256 + tid;
      int row = c >> 4, u = c & 15;
      int su = u ^ (row & 7);
      glds16(Kp + (size_t)(kt0 + row) * D + su * 8, &lK[(i * 256 + w * 64) * 8]);
    }
    // ---- stage V^T [128][64] (reg-staged transpose, pair-packed b32 writes)
    {
      s16x8 va[2], vb[2];
#pragma unroll
      for (int t = 0; t < 2; ++t) {
        int idx = t * 256 + tid;
        int p = idx >> 4, d8 = idx & 15;
        const unsigned short* vp = Vp + (size_t)(kt0 + p * 2) * D + d8 * 8;
        va[t] = *(const s16x8*)vp;
        vb[t] = *(const s16x8*)(vp + D);
      }
#pragma unroll
      for (int t = 0; t < 2; ++t) {
        int idx = t * 256 + tid;
        int p = idx >> 4, d8 = idx & 15;
#pragma unroll
        for (int j = 0; j < 8; ++j) {
          int d = d8 * 8 + j;
          int up = (p >> 2) ^ j ^ (d8 & 7);     // u ^ f(d), f(d)=(d&7)^((d>>3)&7)
          unsigned int word = (unsigned int)(unsigned short)va[t][j] |
                              ((unsigned int)(unsigned short)vb[t][j] << 16);
          *(unsigned int*)&lVT[d * 64 + up * 8 + (p & 3) * 2] = word;
        }
      }
    }
    __syncthreads();                 // staging visible
    if (kt0 > q0 + 31) continue;     // wave fully masked; barriers stay aligned

    // ---- S^T = mfma32(K, Q): st0 (kv 0..31), st1 (kv 32..63)
    fx16 st0 = zf, st1 = zf;
#pragma unroll
    for (int ss = 0; ss < 8; ++ss) {
      int uoff = ((2 * ss + H) ^ (lam & 7)) * 8;
      s16x8 k0 = *(const s16x8*)&lK[lam * 128 + uoff];
      s16x8 k1 = *(const s16x8*)&lK[(32 + lam) * 128 + uoff];
      st0 = mfma32(k0, qf[ss], st0);
      st1 = mfma32(k1, qf[ss], st1);
    }

    // ---- causal mask: lane holds kv = kt0 + {0,32} + (r&3)+8*(r>>2)+4H for q
    if (kt0 + 63 > q0) {
      const int kb = kt0 + 4 * H;
#pragma unroll
      for (int r = 0; r < 16; ++r) {
        int kv = kb + (r & 3) + 8 * (r >> 2);
        if (kv > q) st0[r] = -1e30f;
        if (kv + 32 > q) st1[r] = -1e30f;
      }
    }

    // ---- online softmax (exp2 domain), T13 defer-max (THR=12 ~ e^8.3)
    float pmax = st0[0];
#pragma unroll
    for (int r = 1; r < 16; ++r) pmax = fmaxf(pmax, st0[r]);
#pragma unroll
    for (int r = 0; r < 16; ++r) pmax = fmaxf(pmax, st1[r]);
    pmax = fmaxf(pmax, __shfl_xor(pmax, 32, 64));
    if (!__all(pmax <= mrun + 12.f)) {
      float mnew = fmaxf(mrun, pmax);
      float al = exp2f(mrun - mnew);
      mrun = mnew;
      lrun *= al;
#pragma unroll
      for (int r = 0; r < 16; ++r) {
        o[0][r] *= al; o[1][r] *= al; o[2][r] *= al; o[3][r] *= al;
      }
    }
    float lloc = 0.f;
#pragma unroll
    for (int r = 0; r < 16; ++r) { st0[r] = exp2f(st0[r] - mrun); lloc += st0[r]; }
#pragma unroll
    for (int r = 0; r < 16; ++r) { st1[r] = exp2f(st1[r] - mrun); lloc += st1[r]; }
    lrun += lloc;   // partial (this half's share); combined in epilogue

    // ---- pack P to bf16 pair-words; exchange halves (1 shfl_xor(32) per word)
    unsigned int w0[8], w1[8], w0s[8], w1s[8];
#pragma unroll
    for (int m = 0; m < 8; ++m) {
      w0[m] = (unsigned int)f2bf(st0[2 * m]) | ((unsigned int)f2bf(st0[2 * m + 1]) << 16);
      w1[m] = (unsigned int)f2bf(st1[2 * m]) | ((unsigned int)f2bf(st1[2 * m + 1]) << 16);
    }
#pragma unroll
    for (int m = 0; m < 8; ++m) {
      w0s[m] = __shfl_xor(w0[m], 32, 64);
      w1s[m] = __shfl_xor(w1[m], 32, 64);
    }

    // ---- PV: O^T += mfma32(V^T_frag, P_frag) over 4 kv-chunks of 16
    const bool Hi = (H != 0);
#pragma unroll
    for (int c = 0; c < 4; ++c) {
      union { s16x8 v; unsigned int u[4]; } pb;
      if (c < 2) {
        const int a = 4 * (c & 1);
        pb.u[0] = Hi ? w0s[a + 2] : w0[a + 0];
        pb.u[1] = Hi ? w0s[a + 3] : w0[a + 1];
        pb.u[2] = Hi ? w0[a + 2] : w0s[a + 0];
        pb.u[3] = Hi ? w0[a + 3] : w0s[a + 1];
      } else {
        const int a = 4 * (c & 1);
        pb.u[0] = Hi ? w1s[a + 2] : w1[a + 0];
        pb.u[1] = Hi ? w1s[a + 3] : w1[a + 1];
        pb.u[2] = Hi ? w1[a + 2] : w1s[a + 0];
        pb.u[3] = Hi ? w1[a + 3] : w1s[a + 1];
      }
#pragma unroll
      for (int dt = 0; dt < 4; ++dt) {
        int d = dt * 32 + lam;
        int fd = (lam & 7) ^ ((dt * 4 + (lam >> 3)) & 7);
        s16x8 vf = *(const s16x8*)&lVT[d * 64 + ((2 * c + H) ^ fd) * 8];
        o[dt] = mfma32(vf, pb.v, o[dt]);
      }
    }
  }

  // ---- epilogue: combine l across halves, normalize, write O[q][d]
  lrun += __shfl_xor(lrun, 32, 64);
  float inv = 1.f / lrun;
  unsigned short* orow = O + base + (size_t)q * D;
#pragma unroll
  for (int dt = 0; dt < 4; ++dt)
#pragma unroll
    for (int rq = 0; rq < 4; ++rq) {
      u16x4 ov;
#pragma unroll
      for (int j = 0; j < 4; ++j) ov[j] = f2bf(o[dt][rq * 4 + j] * inv);
      *(u16x4*)(orow + dt * 32 + rq * 8 + H * 4) = ov;
    }
}

// ---------- launch ----------
extern "C" void kernel_launch(void* const* d_in, const int* in_sizes, int n_in,
                              void* d_out, int out_size, void* d_ws, size_t ws_size,
                              hipStream_t stream) {
  (void)in_sizes; (void)n_in; (void)out_size; (void)ws_size;
  const float* x  = (const float*)d_in[0];
  const float* Wq = (const float*)d_in[1];
  const float* Wk = (const float*)d_in[2];
  const float* Wv = (const float*)d_in[3];
  const float* Wo = (const float*)d_in[4];
  const float* gq = (const float*)d_in[5];
  const float* gk = (const float*)d_in[6];
  float* out = (float*)d_out;

  // workspace layout (bytes): peak 136 MB
  char* W = (char*)d_ws;
  unsigned short* xb    = (unsigned short*)(W);                       // 32 MB  x bf16 (later reused for attn out)
  unsigned short* wslot = (unsigned short*)(W + (size_t)33554432);    //  8 MB  current weight bf16
  unsigned short* Qb    = (unsigned short*)(W + (size_t)41943040);    // 32 MB
  unsigned short* Kb    = (unsigned short*)(W + (size_t)75497472);    // 32 MB
  unsigned short* Vb    = (unsigned short*)(W + (size_t)109051904);   // 32 MB
  unsigned short* AO    = xb;                                         // attn out reuses x region

  const dim3 gg(16, 64);   // N/128, M/128

  cvt_kernel<<<4096, 256, 0, stream>>>(x, xb, 16777216);

  cvt_kernel<<<4096, 256, 0, stream>>>(Wq, wslot, 4194304);
  gemm_bt<true><<<gg, 256, 0, stream>>>(xb, wslot, Qb, 8192, 2048, 2048);
  cvt_kernel<<<4096, 256, 0, stream>>>(Wk, wslot, 4194304);
  gemm_bt<true><<<gg, 256, 0, stream>>>(xb, wslot, Kb, 8192, 2048, 2048);
  cvt_kernel<<<4096, 256, 0, stream>>>(Wv, wslot, 4194304);
  gemm_bt<true><<<gg, 256, 0, stream>>>(xb, wslot, Vb, 8192, 2048, 2048);

  // fold hd^-0.5 * log2(e) into Q (softmax runs in exp2 domain)
  rms_kernel<<<32768, 256, 0, stream>>>(Qb, gq, (float)(0.08838834764831845 * 1.4426950408889634));
  rms_kernel<<<32768, 256, 0, stream>>>(Kb, gk, 1.0f);

  attn_kernel<<<dim3(16, 64), 256, 0, stream>>>(Qb, Kb, Vb, AO);

  cvt_kernel<<<4096, 256, 0, stream>>>(Wo, wslot, 4194304);
  gemm_bt<false><<<gg, 256, 0, stream>>>(AO, wslot, out, 8192, 2048, 2048);
}

// Round 3
// 541.851 us; speedup vs baseline: 1.2585x; 1.1161x over previous
//
#include <hip/hip_runtime.h>

// ---------- types ----------
typedef short  s16x8 __attribute__((ext_vector_type(8)));
typedef __bf16 bf16x8 __attribute__((ext_vector_type(8)));
typedef float  fx4   __attribute__((ext_vector_type(4)));
typedef float  fx16  __attribute__((ext_vector_type(16)));
typedef unsigned short u16x4 __attribute__((ext_vector_type(4)));

__device__ __forceinline__ fx4 mfma_bf16(s16x8 a, s16x8 b, fx4 c) {
  return __builtin_amdgcn_mfma_f32_16x16x32_bf16(
      __builtin_bit_cast(bf16x8, a), __builtin_bit_cast(bf16x8, b), c, 0, 0, 0);
}

__device__ __forceinline__ fx16 mfma32(s16x8 a, s16x8 b, fx16 c) {
  return __builtin_amdgcn_mfma_f32_32x32x16_bf16(
      __builtin_bit_cast(bf16x8, a), __builtin_bit_cast(bf16x8, b), c, 0, 0, 0);
}

__device__ __forceinline__ unsigned short f2bf(float f) {
  unsigned int u = __float_as_uint(f);
  u += 0x7fffu + ((u >> 16) & 1u);   // RNE
  return (unsigned short)(u >> 16);
}

__device__ __forceinline__ float bf2f(unsigned int bits16) {
  return __uint_as_float(bits16 << 16);
}

// global -> LDS direct copy, 16B per lane; LDS dest = wave-uniform base + lane*16
__device__ __forceinline__ void glds16(const void* g, void* l) {
  __builtin_amdgcn_global_load_lds(
      (__attribute__((address_space(1))) unsigned int*)g,
      (__attribute__((address_space(3))) unsigned int*)l, 16, 0, 0);
}

// ---------- fp32 -> bf16 conversion ----------
__global__ __launch_bounds__(256) void cvt_kernel(const float* __restrict__ src,
                                                  unsigned short* __restrict__ dst, int n) {
  int nv = n >> 2;
  for (int i = blockIdx.x * blockDim.x + threadIdx.x; i < nv; i += gridDim.x * blockDim.x) {
    fx4 v = ((const fx4*)src)[i];
    u16x4 o;
#pragma unroll
    for (int j = 0; j < 4; ++j) o[j] = f2bf(v[j]);
    ((u16x4*)dst)[i] = o;
  }
}

// ---------- per-head RMSNorm (in place, bf16), wave per (row,head) ----------
__global__ __launch_bounds__(256) void rms_kernel(unsigned short* __restrict__ X,
                                                  const float* __restrict__ g,
                                                  float postscale) {
  int unit = blockIdx.x * 4 + (threadIdx.x >> 6);  // (row*16+head), contiguous 128 elems
  int lane = threadIdx.x & 63;
  unsigned short* p = X + (size_t)unit * 128 + lane * 2;
  unsigned int v = *(const unsigned int*)p;
  float a = bf2f(v & 0xffffu);
  float b = bf2f(v >> 16);
  float ss = a * a + b * b;
#pragma unroll
  for (int m = 32; m >= 1; m >>= 1) ss += __shfl_xor(ss, m, 64);
  float rinv = rsqrtf(ss * (1.0f / 128.0f) + 1e-5f) * postscale;
  float ga = g[lane * 2], gb = g[lane * 2 + 1];
  unsigned int out = (unsigned int)f2bf(a * rinv * ga) |
                     ((unsigned int)f2bf(b * rinv * gb) << 16);
  *(unsigned int*)p = out;
}

// ---------- GEMM: C[M,N] = A[M,K] * B[N,K]^T  (m97 structure: 128x128 tile, BK=32) ----------
template <bool BF16OUT>
__global__ __launch_bounds__(256, 2) void gemm_bt(const unsigned short* __restrict__ A,
                                                  const unsigned short* __restrict__ B,
                                                  void* __restrict__ Cv,
                                                  int M, int N, int K) {
  __shared__ unsigned short lA[128 * 32];
  __shared__ unsigned short lB[128 * 32];
  const int tid = threadIdx.x, w = tid >> 6, lane = tid & 63;
  const int lid = lane & 15, grp = lane >> 4;
  const int wr = w >> 1, wc = w & 1;
  const int tm = blockIdx.y * 128, tn = blockIdx.x * 128;

  fx4 acc[4][4];
#pragma unroll
  for (int i = 0; i < 4; ++i)
#pragma unroll
    for (int j = 0; j < 4; ++j) acc[i][j] = fx4{0.f, 0.f, 0.f, 0.f};

  for (int k0 = 0; k0 < K; k0 += 32) {
    __syncthreads();
#pragma unroll
    for (int i = 0; i < 2; ++i) {
      int c = (w * 2 + i) * 64 + lane;       // 16B chunk id, 512 per tile
      int row = c >> 2, u = c & 3;           // tile row, 16B unit in row (32 elems = 4 units)
      glds16(A + (size_t)(tm + row) * K + k0 + u * 8, &lA[(w * 2 + i) * 512]);
      glds16(B + (size_t)(tn + row) * K + k0 + u * 8, &lB[(w * 2 + i) * 512]);
    }
    __syncthreads();
    s16x8 af[4], bf[4];
#pragma unroll
    for (int mi = 0; mi < 4; ++mi)
      af[mi] = *(const s16x8*)&lA[(wr * 64 + mi * 16 + lid) * 32 + grp * 8];
#pragma unroll
    for (int ni = 0; ni < 4; ++ni)
      bf[ni] = *(const s16x8*)&lB[(wc * 64 + ni * 16 + lid) * 32 + grp * 8];
#pragma unroll
    for (int mi = 0; mi < 4; ++mi)
#pragma unroll
      for (int ni = 0; ni < 4; ++ni)
        acc[mi][ni] = mfma_bf16(af[mi], bf[ni], acc[mi][ni]);
  }

#pragma unroll
  for (int mi = 0; mi < 4; ++mi)
#pragma unroll
    for (int ni = 0; ni < 4; ++ni) {
      const int row = tm + wr * 64 + mi * 16 + grp * 4;
      const int col = tn + wc * 64 + ni * 16 + lid;
#pragma unroll
      for (int j = 0; j < 4; ++j) {
        if constexpr (BF16OUT)
          ((unsigned short*)Cv)[(size_t)(row + j) * N + col] = f2bf(acc[mi][ni][j]);
        else
          ((float*)Cv)[(size_t)(row + j) * N + col] = acc[mi][ni][j];
      }
    }
}

// ---------- causal flash attention ----------
// 32x32 MFMA, QBLK=32/wave, KVBLK=64, 4 waves/block.
// Triangle pairing: block jx handles q-tiles {15-jx, jx} -> constant 34 steps/block.
// Double-buffered K/V staging: next tile's loads issued before current compute (2-phase),
// V ds_writes after compute (T14 split). One barrier per step.
// Swapped MFMAs: S^T = mfma32(K,Q) [col=lane&31=q, row=(r&3)+8(r>>2)+4H = kv mod 32],
// O^T = mfma32(V^T, P). Q pre-scaled by hd^-0.5*log2(e); softmax in exp2 domain.
__global__ __launch_bounds__(256, 2) void attn_kernel(const unsigned short* __restrict__ Q,
                                                      const unsigned short* __restrict__ Kg,
                                                      const unsigned short* __restrict__ Vg,
                                                      unsigned short* __restrict__ O) {
  const int D = 2048, T = 2048;
  __shared__ unsigned short lK[2][64 * 128];   // XOR-swizzled: unit u stores logical u^(row&7)
  __shared__ unsigned short lVT[2][128 * 64];  // V^T, unit u' = u ^ ((d&7)^((d>>3)&7))

  const int tid = threadIdx.x, w = tid >> 6, lane = tid & 63;
  const int lam = lane & 31, H = lane >> 5;
  const int jx = blockIdx.x;
  const int b = blockIdx.y >> 4, h = blockIdx.y & 15;
  const size_t base = (size_t)b * T * D + (size_t)h * 128;
  const unsigned short* Qp = Q + base;
  const unsigned short* Kp = Kg + base;
  const unsigned short* Vp = Vg + base;

  fx16 zf;
#pragma unroll
  for (int i = 0; i < 16; ++i) zf[i] = 0.f;

  s16x8 va[2], vb[2];   // in-flight V stage regs

  for (int pass = 0; pass < 2; ++pass) {
    const int qt = (pass == 0) ? (15 - jx) : jx;
    const int qb = qt * 128;
    const int q0 = qb + w * 32;
    const int q = q0 + lam;
    const int nsteps = qt * 2 + 2;

    // hoist Q fragments: qf[s] = Q[q][s*16 + H*8 .. +7]
    s16x8 qf[8];
    {
      const unsigned short* qrow = Qp + (size_t)q * D + H * 8;
#pragma unroll
      for (int s = 0; s < 8; ++s) qf[s] = *(const s16x8*)(qrow + s * 16);
    }

    fx16 o[4] = {zf, zf, zf, zf};
    float mrun = -1e30f, lrun = 0.f;

    // ---- staging helpers
    auto vloadV = [&](int kt0) {
#pragma unroll
      for (int t = 0; t < 2; ++t) {
        int idx = t * 256 + tid;
        int p = idx >> 4, d8 = idx & 15;
        const unsigned short* vp = Vp + (size_t)(kt0 + p * 2) * D + d8 * 8;
        va[t] = *(const s16x8*)vp;
        vb[t] = *(const s16x8*)(vp + D);
      }
    };
    auto vwriteV = [&](int bsel) {
#pragma unroll
      for (int t = 0; t < 2; ++t) {
        int idx = t * 256 + tid;
        int p = idx >> 4, d8 = idx & 15;
#pragma unroll
        for (int j = 0; j < 8; ++j) {
          int d = d8 * 8 + j;
          int up = (p >> 2) ^ j ^ (d8 & 7);     // u ^ f(d), f(d)=(d&7)^((d>>3)&7)
          unsigned int word = (unsigned int)(unsigned short)va[t][j] |
                              ((unsigned int)(unsigned short)vb[t][j] << 16);
          *(unsigned int*)&lVT[bsel][d * 64 + up * 8 + (p & 3) * 2] = word;
        }
      }
    };
    auto stageK = [&](int bsel, int kt0) {
#pragma unroll
      for (int i = 0; i < 4; ++i) {
        int c = i * 256 + tid;
        int row = c >> 4, u = c & 15;
        int su = u ^ (row & 7);
        glds16(Kp + (size_t)(kt0 + row) * D + su * 8, &lK[bsel][(i * 256 + w * 64) * 8]);
      }
    };

    // ---- prologue: stage step 0 into buffer 0
    vloadV(0);
    stageK(0, 0);
    vwriteV(0);
    __syncthreads();

    for (int s = 0; s < nsteps; ++s) {
      const int kt0 = s << 6;
      const int cur = s & 1, nxt = cur ^ 1;

      // issue next tile's loads (overlap with compute below)
      if (s + 1 < nsteps) {
        vloadV((s + 1) << 6);
        stageK(nxt, (s + 1) << 6);
      }

      if (kt0 <= q0 + 31) {   // wave has unmasked work this step
        // ---- S^T = mfma32(K, Q): st0 (kv 0..31), st1 (kv 32..63)
        fx16 st0 = zf, st1 = zf;
#pragma unroll
        for (int ss = 0; ss < 8; ++ss) {
          int uoff = ((2 * ss + H) ^ (lam & 7)) * 8;
          s16x8 k0 = *(const s16x8*)&lK[cur][lam * 128 + uoff];
          s16x8 k1 = *(const s16x8*)&lK[cur][(32 + lam) * 128 + uoff];
          st0 = mfma32(k0, qf[ss], st0);
          st1 = mfma32(k1, qf[ss], st1);
        }

        // ---- causal mask
        if (kt0 + 63 > q0) {
          const int kb = kt0 + 4 * H;
#pragma unroll
          for (int r = 0; r < 16; ++r) {
            int kv = kb + (r & 3) + 8 * (r >> 2);
            if (kv > q) st0[r] = -1e30f;
            if (kv + 32 > q) st1[r] = -1e30f;
          }
        }

        // ---- online softmax (exp2 domain), T13 defer-max
        float pmax = st0[0];
#pragma unroll
        for (int r = 1; r < 16; ++r) pmax = fmaxf(pmax, st0[r]);
#pragma unroll
        for (int r = 0; r < 16; ++r) pmax = fmaxf(pmax, st1[r]);
        pmax = fmaxf(pmax, __shfl_xor(pmax, 32, 64));
        if (!__all(pmax <= mrun + 12.f)) {
          float mnew = fmaxf(mrun, pmax);
          float al = exp2f(mrun - mnew);
          mrun = mnew;
          lrun *= al;
#pragma unroll
          for (int r = 0; r < 16; ++r) {
            o[0][r] *= al; o[1][r] *= al; o[2][r] *= al; o[3][r] *= al;
          }
        }
        float lloc = 0.f;
#pragma unroll
        for (int r = 0; r < 16; ++r) { st0[r] = exp2f(st0[r] - mrun); lloc += st0[r]; }
#pragma unroll
        for (int r = 0; r < 16; ++r) { st1[r] = exp2f(st1[r] - mrun); lloc += st1[r]; }
        lrun += lloc;   // this half's share; combined in epilogue

        // ---- pack P to bf16 pair-words; exchange halves
        unsigned int w0[8], w1[8], w0s[8], w1s[8];
#pragma unroll
        for (int m = 0; m < 8; ++m) {
          w0[m] = (unsigned int)f2bf(st0[2 * m]) | ((unsigned int)f2bf(st0[2 * m + 1]) << 16);
          w1[m] = (unsigned int)f2bf(st1[2 * m]) | ((unsigned int)f2bf(st1[2 * m + 1]) << 16);
        }
#pragma unroll
        for (int m = 0; m < 8; ++m) {
          w0s[m] = __shfl_xor(w0[m], 32, 64);
          w1s[m] = __shfl_xor(w1[m], 32, 64);
        }

        // ---- PV: O^T += mfma32(V^T_frag, P_frag) over 4 kv-chunks of 16
        const bool Hi = (H != 0);
#pragma unroll
        for (int c = 0; c < 4; ++c) {
          union { s16x8 v; unsigned int u[4]; } pb;
          if (c < 2) {
            const int a = 4 * (c & 1);
            pb.u[0] = Hi ? w0s[a + 2] : w0[a + 0];
            pb.u[1] = Hi ? w0s[a + 3] : w0[a + 1];
            pb.u[2] = Hi ? w0[a + 2] : w0s[a + 0];
            pb.u[3] = Hi ? w0[a + 3] : w0s[a + 1];
          } else {
            const int a = 4 * (c & 1);
            pb.u[0] = Hi ? w1s[a + 2] : w1[a + 0];
            pb.u[1] = Hi ? w1s[a + 3] : w1[a + 1];
            pb.u[2] = Hi ? w1[a + 2] : w1s[a + 0];
            pb.u[3] = Hi ? w1[a + 3] : w1s[a + 1];
          }
#pragma unroll
          for (int dt = 0; dt < 4; ++dt) {
            int d = dt * 32 + lam;
            int fd = (lam & 7) ^ ((dt * 4 + (lam >> 3)) & 7);
            s16x8 vf = *(const s16x8*)&lVT[cur][d * 64 + ((2 * c + H) ^ fd) * 8];
            o[dt] = mfma32(vf, pb.v, o[dt]);
          }
        }
      }

      // write next V tile into LDS (loads have had the whole compute to land)
      if (s + 1 < nsteps) vwriteV(nxt);
      __syncthreads();
    }

    // ---- epilogue: combine l across halves, normalize, write O[q][d]
    lrun += __shfl_xor(lrun, 32, 64);
    float inv = 1.f / lrun;
    unsigned short* orow = O + base + (size_t)q * D;
#pragma unroll
    for (int dt = 0; dt < 4; ++dt)
#pragma unroll
      for (int rq = 0; rq < 4; ++rq) {
        u16x4 ov;
#pragma unroll
        for (int j = 0; j < 4; ++j) ov[j] = f2bf(o[dt][rq * 4 + j] * inv);
        *(u16x4*)(orow + dt * 32 + rq * 8 + H * 4) = ov;
      }
  }
}

// ---------- launch ----------
extern "C" void kernel_launch(void* const* d_in, const int* in_sizes, int n_in,
                              void* d_out, int out_size, void* d_ws, size_t ws_size,
                              hipStream_t stream) {
  (void)in_sizes; (void)n_in; (void)out_size; (void)ws_size;
  const float* x  = (const float*)d_in[0];
  const float* Wq = (const float*)d_in[1];
  const float* Wk = (const float*)d_in[2];
  const float* Wv = (const float*)d_in[3];
  const float* Wo = (const float*)d_in[4];
  const float* gq = (const float*)d_in[5];
  const float* gk = (const float*)d_in[6];
  float* out = (float*)d_out;

  // workspace layout (bytes): peak 136 MB
  char* W = (char*)d_ws;
  unsigned short* xb    = (unsigned short*)(W);                       // 32 MB  x bf16 (later reused for attn out)
  unsigned short* wslot = (unsigned short*)(W + (size_t)33554432);    //  8 MB  current weight bf16
  unsigned short* Qb    = (unsigned short*)(W + (size_t)41943040);    // 32 MB
  unsigned short* Kb    = (unsigned short*)(W + (size_t)75497472);    // 32 MB
  unsigned short* Vb    = (unsigned short*)(W + (size_t)109051904);   // 32 MB
  unsigned short* AO    = xb;                                         // attn out reuses x region

  const dim3 gg(16, 64);   // N/128, M/128

  cvt_kernel<<<4096, 256, 0, stream>>>(x, xb, 16777216);

  cvt_kernel<<<4096, 256, 0, stream>>>(Wq, wslot, 4194304);
  gemm_bt<true><<<gg, 256, 0, stream>>>(xb, wslot, Qb, 8192, 2048, 2048);
  cvt_kernel<<<4096, 256, 0, stream>>>(Wk, wslot, 4194304);
  gemm_bt<true><<<gg, 256, 0, stream>>>(xb, wslot, Kb, 8192, 2048, 2048);
  cvt_kernel<<<4096, 256, 0, stream>>>(Wv, wslot, 4194304);
  gemm_bt<true><<<gg, 256, 0, stream>>>(xb, wslot, Vb, 8192, 2048, 2048);

  // fold hd^-0.5 * log2(e) into Q (softmax runs in exp2 domain)
  rms_kernel<<<32768, 256, 0, stream>>>(Qb, gq, (float)(0.08838834764831845 * 1.4426950408889634));
  rms_kernel<<<32768, 256, 0, stream>>>(Kb, gk, 1.0f);

  attn_kernel<<<dim3(8, 64), 256, 0, stream>>>(Qb, Kb, Vb, AO);

  cvt_kernel<<<4096, 256, 0, stream>>>(Wo, wslot, 4194304);
  gemm_bt<false><<<gg, 256, 0, stream>>>(AO, wslot, out, 8192, 2048, 2048);
}

// Round 4
// 522.288 us; speedup vs baseline: 1.3057x; 1.0375x over previous
//
#include <hip/hip_runtime.h>

// ---------- types ----------
typedef short  s16x8 __attribute__((ext_vector_type(8)));
typedef __bf16 bf16x8 __attribute__((ext_vector_type(8)));
typedef float  fx4   __attribute__((ext_vector_type(4)));
typedef float  fx16  __attribute__((ext_vector_type(16)));
typedef unsigned short u16x4 __attribute__((ext_vector_type(4)));
typedef unsigned int   u32x2 __attribute__((ext_vector_type(2)));
typedef unsigned int   u32x4 __attribute__((ext_vector_type(4)));

__device__ __forceinline__ fx4 mfma_bf16(s16x8 a, s16x8 b, fx4 c) {
  return __builtin_amdgcn_mfma_f32_16x16x32_bf16(
      __builtin_bit_cast(bf16x8, a), __builtin_bit_cast(bf16x8, b), c, 0, 0, 0);
}

__device__ __forceinline__ fx16 mfma32(s16x8 a, s16x8 b, fx16 c) {
  return __builtin_amdgcn_mfma_f32_32x32x16_bf16(
      __builtin_bit_cast(bf16x8, a), __builtin_bit_cast(bf16x8, b), c, 0, 0, 0);
}

__device__ __forceinline__ unsigned short f2bf(float f) {
  unsigned int u = __float_as_uint(f);
  u += 0x7fffu + ((u >> 16) & 1u);   // RNE
  return (unsigned short)(u >> 16);
}

__device__ __forceinline__ float bf2f(unsigned int bits16) {
  return __uint_as_float(bits16 << 16);
}

// packed f32x2 -> bf16x2 (RNE), T12 primitive (no builtin on gfx950)
__device__ __forceinline__ unsigned int cvtpk(float lo, float hi) {
  unsigned int r;
  asm volatile("v_cvt_pk_bf16_f32 %0, %1, %2" : "=v"(r) : "v"(lo), "v"(hi));
  return r;
}

// global -> LDS direct copy, 16B per lane; LDS dest = wave-uniform base + lane*16
__device__ __forceinline__ void glds16(const void* g, void* l) {
  __builtin_amdgcn_global_load_lds(
      (__attribute__((address_space(1))) unsigned int*)g,
      (__attribute__((address_space(3))) unsigned int*)l, 16, 0, 0);
}

// ---------- fp32 -> bf16 conversion ----------
__global__ __launch_bounds__(256) void cvt_kernel(const float* __restrict__ src,
                                                  unsigned short* __restrict__ dst, int n) {
  int nv = n >> 2;
  for (int i = blockIdx.x * blockDim.x + threadIdx.x; i < nv; i += gridDim.x * blockDim.x) {
    fx4 v = ((const fx4*)src)[i];
    u16x4 o;
#pragma unroll
    for (int j = 0; j < 4; ++j) o[j] = f2bf(v[j]);
    ((u16x4*)dst)[i] = o;
  }
}

// ---------- per-head RMSNorm (in place, bf16), 16 lanes per 128-elem unit ----------
__global__ __launch_bounds__(256) void rms_kernel(unsigned short* __restrict__ X,
                                                  const float* __restrict__ g,
                                                  float postscale) {
  int unit = blockIdx.x * 16 + (threadIdx.x >> 4);
  int e8 = threadIdx.x & 15;
  unsigned short* p = X + (size_t)unit * 128 + e8 * 8;
  s16x8 v = *(const s16x8*)p;
  float f[8];
  float ss = 0.f;
#pragma unroll
  for (int j = 0; j < 8; ++j) {
    f[j] = bf2f((unsigned short)v[j]);
    ss += f[j] * f[j];
  }
#pragma unroll
  for (int m = 8; m >= 1; m >>= 1) ss += __shfl_xor(ss, m, 64);  // within 16-lane group
  float rinv = rsqrtf(ss * (1.0f / 128.0f) + 1e-5f) * postscale;
  const fx4* gv = (const fx4*)(g + e8 * 8);
  fx4 g0 = gv[0], g1 = gv[1];
  u32x4 ow;
  ow[0] = cvtpk(f[0] * rinv * g0[0], f[1] * rinv * g0[1]);
  ow[1] = cvtpk(f[2] * rinv * g0[2], f[3] * rinv * g0[3]);
  ow[2] = cvtpk(f[4] * rinv * g1[0], f[5] * rinv * g1[1]);
  ow[3] = cvtpk(f[6] * rinv * g1[2], f[7] * rinv * g1[3]);
  *(u32x4*)p = ow;
}

// ---------- GEMM: C[M,N] = A[M,K] * B[N,K]^T ----------
// 256x256 tile, BK=64, 8 waves (2m x 4n), dbuf LDS 128 KiB, XOR-swizzled units.
// Counted vmcnt(8) at iteration top (never 0 in main loop); tile kt+2 staged after
// the final barrier of iteration kt (no readers of that buffer remain).
// 4 MFMA phases per K-tile, raw s_barrier pairs + setprio around each cluster.
template <bool BF16OUT>
__global__ __launch_bounds__(512, 2) void gemm256(const unsigned short* __restrict__ A,
                                                  const unsigned short* __restrict__ B,
                                                  void* __restrict__ Cv,
                                                  int M, int N, int K) {
  __shared__ unsigned short lA[2][256 * 64];
  __shared__ unsigned short lB[2][256 * 64];
  const int tid = threadIdx.x, w = tid >> 6, lane = tid & 63;
  const int lid = lane & 15, grp = lane >> 4;
  const int wr = w >> 2, wc = w & 3;
  const int tm = blockIdx.y * 256, tn = blockIdx.x * 256;

  auto stage = [&](int buf, int kt) {
    const int k0 = kt * 64;
#pragma unroll
    for (int i = 0; i < 4; ++i) {
      int c = i * 512 + tid;
      int row = c >> 3, u = c & 7;
      int su = u ^ (row & 7);
      glds16(A + (size_t)(tm + row) * K + k0 + su * 8, &lA[buf][(i * 512 + w * 64) * 8]);
    }
#pragma unroll
    for (int i = 0; i < 4; ++i) {
      int c = i * 512 + tid;
      int row = c >> 3, u = c & 7;
      int su = u ^ (row & 7);
      glds16(B + (size_t)(tn + row) * K + k0 + su * 8, &lB[buf][(i * 512 + w * 64) * 8]);
    }
  };

  fx4 acc[8][4];
#pragma unroll
  for (int i = 0; i < 8; ++i)
#pragma unroll
    for (int j = 0; j < 4; ++j) acc[i][j] = fx4{0.f, 0.f, 0.f, 0.f};

  stage(0, 0);
  stage(1, 1);

  const int NT = K >> 6;
  for (int kt = 0; kt < NT; ++kt) {
    const int cur = kt & 1;
    if (kt < NT - 1) {
      asm volatile("s_waitcnt vmcnt(8)" ::: "memory");   // tile kt landed; kt+1 in flight
    } else {
      asm volatile("s_waitcnt vmcnt(0)" ::: "memory");   // last tile
    }
    __builtin_amdgcn_s_barrier();                        // all waves see tile kt in LDS
    __builtin_amdgcn_sched_barrier(0);

    const unsigned short* la = &lA[cur][0];
    const unsigned short* lb = &lB[cur][0];

    // B fragments for the whole K-tile (reused by all 4 phases)
    s16x8 bfr[4][2];
#pragma unroll
    for (int ni = 0; ni < 4; ++ni)
#pragma unroll
      for (int ks = 0; ks < 2; ++ks) {
        int row = wc * 64 + ni * 16 + lid;
        int u = (ks * 4 + grp) ^ (row & 7);
        bfr[ni][ks] = *(const s16x8*)&lb[row * 64 + u * 8];
      }

#pragma unroll
    for (int p = 0; p < 4; ++p) {
      s16x8 af[2][2];
#pragma unroll
      for (int mi = 0; mi < 2; ++mi)
#pragma unroll
        for (int ks = 0; ks < 2; ++ks) {
          int row = wr * 128 + (p * 2 + mi) * 16 + lid;
          int u = (ks * 4 + grp) ^ (row & 7);
          af[mi][ks] = *(const s16x8*)&la[row * 64 + u * 8];
        }
      __builtin_amdgcn_s_barrier();
      __builtin_amdgcn_s_setprio(1);
#pragma unroll
      for (int mi = 0; mi < 2; ++mi)
#pragma unroll
        for (int ni = 0; ni < 4; ++ni)
#pragma unroll
          for (int ks = 0; ks < 2; ++ks)
            acc[p * 2 + mi][ni] = mfma_bf16(af[mi][ks], bfr[ni][ks], acc[p * 2 + mi][ni]);
      __builtin_amdgcn_s_setprio(0);
      __builtin_amdgcn_s_barrier();
    }

    if (kt + 2 < NT) stage(cur, kt + 2);   // after final barrier: no readers of buf[cur]
  }

#pragma unroll
  for (int mi = 0; mi < 8; ++mi)
#pragma unroll
    for (int ni = 0; ni < 4; ++ni) {
      const int row = tm + wr * 128 + mi * 16 + grp * 4;
      const int col = tn + wc * 64 + ni * 16 + lid;
#pragma unroll
      for (int j = 0; j < 4; ++j) {
        if constexpr (BF16OUT)
          ((unsigned short*)Cv)[(size_t)(row + j) * N + col] = f2bf(acc[mi][ni][j]);
        else
          ((float*)Cv)[(size_t)(row + j) * N + col] = acc[mi][ni][j];
      }
    }
}

// ---------- causal flash attention ----------
// 32x32 MFMA, QBLK=32/wave, KVBLK=64, 4 waves/block.
// Triangle pairing: block jx handles q-tiles {15-jx, jx} -> constant 34 steps/block.
// Double-buffered K/V staging; V ds_writes after compute (T14 split). One barrier/step.
// S^T = mfma32(K,Q); O^T = mfma32(V^T, P). Q pre-scaled by hd^-0.5*log2(e).
__global__ __launch_bounds__(256, 2) void attn_kernel(const unsigned short* __restrict__ Q,
                                                      const unsigned short* __restrict__ Kg,
                                                      const unsigned short* __restrict__ Vg,
                                                      unsigned short* __restrict__ O) {
  const int D = 2048, T = 2048;
  __shared__ unsigned short lK[2][64 * 128];   // XOR-swizzled: unit u stores logical u^(row&7)
  __shared__ unsigned short lVT[2][128 * 64];  // V^T, unit u' = u ^ ((d&7)^((d>>3)&7))

  const int tid = threadIdx.x, w = tid >> 6, lane = tid & 63;
  const int lam = lane & 31, H = lane >> 5;
  const int jx = blockIdx.x;
  const int b = blockIdx.y >> 4, h = blockIdx.y & 15;
  const size_t base = (size_t)b * T * D + (size_t)h * 128;
  const unsigned short* Qp = Q + base;
  const unsigned short* Kp = Kg + base;
  const unsigned short* Vp = Vg + base;

  fx16 zf;
#pragma unroll
  for (int i = 0; i < 16; ++i) zf[i] = 0.f;

  s16x8 va[2], vb[2];   // in-flight V stage regs

  for (int pass = 0; pass < 2; ++pass) {
    const int qt = (pass == 0) ? (15 - jx) : jx;
    const int qb = qt * 128;
    const int q0 = qb + w * 32;
    const int q = q0 + lam;
    const int nsteps = qt * 2 + 2;

    s16x8 qf[8];
    {
      const unsigned short* qrow = Qp + (size_t)q * D + H * 8;
#pragma unroll
      for (int s = 0; s < 8; ++s) qf[s] = *(const s16x8*)(qrow + s * 16);
    }

    fx16 o[4] = {zf, zf, zf, zf};
    float mrun = -1e30f, lrun = 0.f;

    auto vloadV = [&](int kt0) {
#pragma unroll
      for (int t = 0; t < 2; ++t) {
        int idx = t * 256 + tid;
        int p = idx >> 4, d8 = idx & 15;
        const unsigned short* vp = Vp + (size_t)(kt0 + p * 2) * D + d8 * 8;
        va[t] = *(const s16x8*)vp;
        vb[t] = *(const s16x8*)(vp + D);
      }
    };
    auto vwriteV = [&](int bsel) {
#pragma unroll
      for (int t = 0; t < 2; ++t) {
        int idx = t * 256 + tid;
        int p = idx >> 4, d8 = idx & 15;
#pragma unroll
        for (int j = 0; j < 8; ++j) {
          int d = d8 * 8 + j;
          int up = (p >> 2) ^ j ^ (d8 & 7);     // u ^ f(d), f(d)=(d&7)^((d>>3)&7)
          unsigned int word = (unsigned int)(unsigned short)va[t][j] |
                              ((unsigned int)(unsigned short)vb[t][j] << 16);
          *(unsigned int*)&lVT[bsel][d * 64 + up * 8 + (p & 3) * 2] = word;
        }
      }
    };
    auto stageK = [&](int bsel, int kt0) {
#pragma unroll
      for (int i = 0; i < 4; ++i) {
        int c = i * 256 + tid;
        int row = c >> 4, u = c & 15;
        int su = u ^ (row & 7);
        glds16(Kp + (size_t)(kt0 + row) * D + su * 8, &lK[bsel][(i * 256 + w * 64) * 8]);
      }
    };

    vloadV(0);
    stageK(0, 0);
    vwriteV(0);
    __syncthreads();

    for (int s = 0; s < nsteps; ++s) {
      const int kt0 = s << 6;
      const int cur = s & 1, nxt = cur ^ 1;

      if (s + 1 < nsteps) {
        vloadV((s + 1) << 6);
        stageK(nxt, (s + 1) << 6);
      }

      if (kt0 <= q0 + 31) {
        // ---- S^T = mfma32(K, Q)
        fx16 st0 = zf, st1 = zf;
#pragma unroll
        for (int ss = 0; ss < 8; ++ss) {
          int uoff = ((2 * ss + H) ^ (lam & 7)) * 8;
          s16x8 k0 = *(const s16x8*)&lK[cur][lam * 128 + uoff];
          s16x8 k1 = *(const s16x8*)&lK[cur][(32 + lam) * 128 + uoff];
          st0 = mfma32(k0, qf[ss], st0);
          st1 = mfma32(k1, qf[ss], st1);
        }

        // ---- causal mask
        if (kt0 + 63 > q0) {
          const int kb = kt0 + 4 * H;
#pragma unroll
          for (int r = 0; r < 16; ++r) {
            int kv = kb + (r & 3) + 8 * (r >> 2);
            if (kv > q) st0[r] = -1e30f;
            if (kv + 32 > q) st1[r] = -1e30f;
          }
        }

        // ---- online softmax (exp2 domain), T13 defer-max; max3-fusable chains
        float pa = fmaxf(st0[0], st0[1]);
        float pb = fmaxf(st0[2], st0[3]);
#pragma unroll
        for (int r = 4; r < 16; r += 4) {
          pa = fmaxf(fmaxf(pa, st0[r]), st0[r + 1]);
          pb = fmaxf(fmaxf(pb, st0[r + 2]), st0[r + 3]);
        }
#pragma unroll
        for (int r = 0; r < 16; r += 4) {
          pa = fmaxf(fmaxf(pa, st1[r]), st1[r + 1]);
          pb = fmaxf(fmaxf(pb, st1[r + 2]), st1[r + 3]);
        }
        float pmax = fmaxf(pa, pb);
        pmax = fmaxf(pmax, __shfl_xor(pmax, 32, 64));
        if (!__all(pmax <= mrun + 12.f)) {
          float mnew = fmaxf(mrun, pmax);
          float al = exp2f(mrun - mnew);
          mrun = mnew;
          lrun *= al;
#pragma unroll
          for (int r = 0; r < 16; ++r) {
            o[0][r] *= al; o[1][r] *= al; o[2][r] *= al; o[3][r] *= al;
          }
        }
        float lloc = 0.f;
#pragma unroll
        for (int r = 0; r < 16; ++r) { st0[r] = exp2f(st0[r] - mrun); lloc += st0[r]; }
#pragma unroll
        for (int r = 0; r < 16; ++r) { st1[r] = exp2f(st1[r] - mrun); lloc += st1[r]; }
        lrun += lloc;

        // ---- pack P to bf16 pair-words (v_cvt_pk), exchange halves
        unsigned int w0[8], w1[8], w0s[8], w1s[8];
#pragma unroll
        for (int m = 0; m < 8; ++m) {
          w0[m] = cvtpk(st0[2 * m], st0[2 * m + 1]);
          w1[m] = cvtpk(st1[2 * m], st1[2 * m + 1]);
        }
#pragma unroll
        for (int m = 0; m < 8; ++m) {
          w0s[m] = __shfl_xor(w0[m], 32, 64);
          w1s[m] = __shfl_xor(w1[m], 32, 64);
        }

        // ---- PV: O^T += mfma32(V^T_frag, P_frag)
        const bool Hi = (H != 0);
#pragma unroll
        for (int c = 0; c < 4; ++c) {
          union { s16x8 v; unsigned int u[4]; } pbu;
          if (c < 2) {
            const int a = 4 * (c & 1);
            pbu.u[0] = Hi ? w0s[a + 2] : w0[a + 0];
            pbu.u[1] = Hi ? w0s[a + 3] : w0[a + 1];
            pbu.u[2] = Hi ? w0[a + 2] : w0s[a + 0];
            pbu.u[3] = Hi ? w0[a + 3] : w0s[a + 1];
          } else {
            const int a = 4 * (c & 1);
            pbu.u[0] = Hi ? w1s[a + 2] : w1[a + 0];
            pbu.u[1] = Hi ? w1s[a + 3] : w1[a + 1];
            pbu.u[2] = Hi ? w1[a + 2] : w1s[a + 0];
            pbu.u[3] = Hi ? w1[a + 3] : w1s[a + 1];
          }
#pragma unroll
          for (int dt = 0; dt < 4; ++dt) {
            int d = dt * 32 + lam;
            int fd = (lam & 7) ^ ((dt * 4 + (lam >> 3)) & 7);
            s16x8 vf = *(const s16x8*)&lVT[cur][d * 64 + ((2 * c + H) ^ fd) * 8];
            o[dt] = mfma32(vf, pbu.v, o[dt]);
          }
        }
      }

      if (s + 1 < nsteps) vwriteV(nxt);
      __syncthreads();
    }

    // ---- epilogue
    lrun += __shfl_xor(lrun, 32, 64);
    float inv = 1.f / lrun;
    unsigned short* orow = O + base + (size_t)q * D;
#pragma unroll
    for (int dt = 0; dt < 4; ++dt)
#pragma unroll
      for (int rq = 0; rq < 4; ++rq) {
        u32x2 uv;
        uv[0] = cvtpk(o[dt][rq * 4 + 0] * inv, o[dt][rq * 4 + 1] * inv);
        uv[1] = cvtpk(o[dt][rq * 4 + 2] * inv, o[dt][rq * 4 + 3] * inv);
        *(u32x2*)(orow + dt * 32 + rq * 8 + H * 4) = uv;
      }
  }
}

// ---------- launch ----------
extern "C" void kernel_launch(void* const* d_in, const int* in_sizes, int n_in,
                              void* d_out, int out_size, void* d_ws, size_t ws_size,
                              hipStream_t stream) {
  (void)in_sizes; (void)n_in; (void)out_size; (void)ws_size;
  const float* x  = (const float*)d_in[0];
  const float* Wq = (const float*)d_in[1];
  const float* Wk = (const float*)d_in[2];
  const float* Wv = (const float*)d_in[3];
  const float* Wo = (const float*)d_in[4];
  const float* gq = (const float*)d_in[5];
  const float* gk = (const float*)d_in[6];
  float* out = (float*)d_out;

  // workspace layout (bytes): peak 136 MB
  char* W = (char*)d_ws;
  unsigned short* xb    = (unsigned short*)(W);                       // 32 MB  x bf16 (later reused for attn out)
  unsigned short* wslot = (unsigned short*)(W + (size_t)33554432);    //  8 MB  current weight bf16
  unsigned short* Qb    = (unsigned short*)(W + (size_t)41943040);    // 32 MB
  unsigned short* Kb    = (unsigned short*)(W + (size_t)75497472);    // 32 MB
  unsigned short* Vb    = (unsigned short*)(W + (size_t)109051904);   // 32 MB
  unsigned short* AO    = xb;                                         // attn out reuses x region

  const dim3 gg(8, 32);   // N/256, M/256

  cvt_kernel<<<4096, 256, 0, stream>>>(x, xb, 16777216);

  cvt_kernel<<<4096, 256, 0, stream>>>(Wq, wslot, 4194304);
  gemm256<true><<<gg, 512, 0, stream>>>(xb, wslot, Qb, 8192, 2048, 2048);
  cvt_kernel<<<4096, 256, 0, stream>>>(Wk, wslot, 4194304);
  gemm256<true><<<gg, 512, 0, stream>>>(xb, wslot, Kb, 8192, 2048, 2048);
  cvt_kernel<<<4096, 256, 0, stream>>>(Wv, wslot, 4194304);
  gemm256<true><<<gg, 512, 0, stream>>>(xb, wslot, Vb, 8192, 2048, 2048);

  // fold hd^-0.5 * log2(e) into Q (softmax runs in exp2 domain)
  rms_kernel<<<8192, 256, 0, stream>>>(Qb, gq, (float)(0.08838834764831845 * 1.4426950408889634));
  rms_kernel<<<8192, 256, 0, stream>>>(Kb, gk, 1.0f);

  attn_kernel<<<dim3(8, 64), 256, 0, stream>>>(Qb, Kb, Vb, AO);

  cvt_kernel<<<4096, 256, 0, stream>>>(Wo, wslot, 4194304);
  gemm256<false><<<gg, 512, 0, stream>>>(AO, wslot, out, 8192, 2048, 2048);
}

// Round 5
// 488.061 us; speedup vs baseline: 1.3972x; 1.0701x over previous
//
#include <hip/hip_runtime.h>

// ---------- types ----------
typedef short  s16x8 __attribute__((ext_vector_type(8)));
typedef __bf16 bf16x8 __attribute__((ext_vector_type(8)));
typedef float  fx4   __attribute__((ext_vector_type(4)));
typedef float  fx16  __attribute__((ext_vector_type(16)));
typedef unsigned short u16x4 __attribute__((ext_vector_type(4)));
typedef unsigned int   u32x2 __attribute__((ext_vector_type(2)));
typedef unsigned int   u32x4 __attribute__((ext_vector_type(4)));

__device__ __forceinline__ fx4 mfma_bf16(s16x8 a, s16x8 b, fx4 c) {
  return __builtin_amdgcn_mfma_f32_16x16x32_bf16(
      __builtin_bit_cast(bf16x8, a), __builtin_bit_cast(bf16x8, b), c, 0, 0, 0);
}

__device__ __forceinline__ fx16 mfma32(s16x8 a, s16x8 b, fx16 c) {
  return __builtin_amdgcn_mfma_f32_32x32x16_bf16(
      __builtin_bit_cast(bf16x8, a), __builtin_bit_cast(bf16x8, b), c, 0, 0, 0);
}

__device__ __forceinline__ unsigned short f2bf(float f) {
  unsigned int u = __float_as_uint(f);
  u += 0x7fffu + ((u >> 16) & 1u);   // RNE
  return (unsigned short)(u >> 16);
}

__device__ __forceinline__ float bf2f(unsigned int bits16) {
  return __uint_as_float(bits16 << 16);
}

// packed f32x2 -> bf16x2 (RNE), T12 primitive (no builtin on gfx950)
__device__ __forceinline__ unsigned int cvtpk(float lo, float hi) {
  unsigned int r;
  asm volatile("v_cvt_pk_bf16_f32 %0, %1, %2" : "=v"(r) : "v"(lo), "v"(hi));
  return r;
}

// global -> LDS direct copy, 16B per lane; LDS dest = wave-uniform base + lane*16
__device__ __forceinline__ void glds16(const void* g, void* l) {
  __builtin_amdgcn_global_load_lds(
      (__attribute__((address_space(1))) unsigned int*)g,
      (__attribute__((address_space(3))) unsigned int*)l, 16, 0, 0);
}

// ---------- fp32 -> bf16 conversion ----------
__global__ __launch_bounds__(256) void cvt_kernel(const float* __restrict__ src,
                                                  unsigned short* __restrict__ dst, int n) {
  int nv = n >> 2;
  for (int i = blockIdx.x * blockDim.x + threadIdx.x; i < nv; i += gridDim.x * blockDim.x) {
    fx4 v = ((const fx4*)src)[i];
    u16x4 o;
#pragma unroll
    for (int j = 0; j < 4; ++j) o[j] = f2bf(v[j]);
    ((u16x4*)dst)[i] = o;
  }
}

// ---------- per-head RMSNorm (in place, bf16), 16 lanes per 128-elem unit ----------
__global__ __launch_bounds__(256) void rms_kernel(unsigned short* __restrict__ X,
                                                  const float* __restrict__ g,
                                                  float postscale) {
  int unit = blockIdx.x * 16 + (threadIdx.x >> 4);
  int e8 = threadIdx.x & 15;
  unsigned short* p = X + (size_t)unit * 128 + e8 * 8;
  s16x8 v = *(const s16x8*)p;
  float f[8];
  float ss = 0.f;
#pragma unroll
  for (int j = 0; j < 8; ++j) {
    f[j] = bf2f((unsigned short)v[j]);
    ss += f[j] * f[j];
  }
#pragma unroll
  for (int m = 8; m >= 1; m >>= 1) ss += __shfl_xor(ss, m, 64);  // within 16-lane group
  float rinv = rsqrtf(ss * (1.0f / 128.0f) + 1e-5f) * postscale;
  const fx4* gv = (const fx4*)(g + e8 * 8);
  fx4 g0 = gv[0], g1 = gv[1];
  u32x4 ow;
  ow[0] = cvtpk(f[0] * rinv * g0[0], f[1] * rinv * g0[1]);
  ow[1] = cvtpk(f[2] * rinv * g0[2], f[3] * rinv * g0[3]);
  ow[2] = cvtpk(f[4] * rinv * g1[0], f[5] * rinv * g1[1]);
  ow[3] = cvtpk(f[6] * rinv * g1[2], f[7] * rinv * g1[3]);
  *(u32x4*)p = ow;
}

// ---------- GEMM: C[M,N] = A[M,K] * B[N,K]^T ----------
// 256x256 tile, BK=64, 8 waves (2m x 4n), dbuf LDS 128 KiB, XOR-swizzled units.
// Counted vmcnt(8) + ONE barrier at tile top (each wave drains its own 8 staging
// loads; barrier publishes the union). NO intra-tile barriers: waves free-run so
// ds_read windows overlap other waves' MFMA windows. One barrier at tile bottom
// (all reads of buf[cur] retired) then stage kt+2 into it. vmcnt never drains to
// 0 in the main loop (T4).
template <bool BF16OUT>
__global__ __launch_bounds__(512, 2) void gemm256(const unsigned short* __restrict__ A,
                                                  const unsigned short* __restrict__ B,
                                                  void* __restrict__ Cv,
                                                  int M, int N, int K) {
  __shared__ unsigned short lA[2][256 * 64];
  __shared__ unsigned short lB[2][256 * 64];
  const int tid = threadIdx.x, w = tid >> 6, lane = tid & 63;
  const int lid = lane & 15, grp = lane >> 4;
  const int wr = w >> 2, wc = w & 3;
  const int tm = blockIdx.y * 256, tn = blockIdx.x * 256;

  auto stage = [&](int buf, int kt) {
    const int k0 = kt * 64;
#pragma unroll
    for (int i = 0; i < 4; ++i) {
      int c = i * 512 + tid;
      int row = c >> 3, u = c & 7;
      int su = u ^ (row & 7);
      glds16(A + (size_t)(tm + row) * K + k0 + su * 8, &lA[buf][(i * 512 + w * 64) * 8]);
    }
#pragma unroll
    for (int i = 0; i < 4; ++i) {
      int c = i * 512 + tid;
      int row = c >> 3, u = c & 7;
      int su = u ^ (row & 7);
      glds16(B + (size_t)(tn + row) * K + k0 + su * 8, &lB[buf][(i * 512 + w * 64) * 8]);
    }
  };

  fx4 acc[8][4];
#pragma unroll
  for (int i = 0; i < 8; ++i)
#pragma unroll
    for (int j = 0; j < 4; ++j) acc[i][j] = fx4{0.f, 0.f, 0.f, 0.f};

  stage(0, 0);
  stage(1, 1);

  const int NT = K >> 6;
  for (int kt = 0; kt < NT; ++kt) {
    const int cur = kt & 1;
    if (kt < NT - 1) {
      asm volatile("s_waitcnt vmcnt(8)" ::: "memory");   // own tile-kt loads landed
    } else {
      asm volatile("s_waitcnt vmcnt(0)" ::: "memory");   // last tile
    }
    __builtin_amdgcn_s_barrier();                        // union of tile kt visible

    const unsigned short* la = &lA[cur][0];
    const unsigned short* lb = &lB[cur][0];

    // B fragments for the whole K-tile (reused by all 4 groups)
    s16x8 bfr[4][2];
#pragma unroll
    for (int ni = 0; ni < 4; ++ni)
#pragma unroll
      for (int ks = 0; ks < 2; ++ks) {
        int row = wc * 64 + ni * 16 + lid;
        int u = (ks * 4 + grp) ^ (row & 7);
        bfr[ni][ks] = *(const s16x8*)&lb[row * 64 + u * 8];
      }

    // 4 MFMA groups, NO barriers between: compiler pipelines group p+1's
    // ds_reads under group p's MFMAs; waves drift so LDS/MFMA pipes overlap.
#pragma unroll
    for (int p = 0; p < 4; ++p) {
      s16x8 af[2][2];
#pragma unroll
      for (int mi = 0; mi < 2; ++mi)
#pragma unroll
        for (int ks = 0; ks < 2; ++ks) {
          int row = wr * 128 + (p * 2 + mi) * 16 + lid;
          int u = (ks * 4 + grp) ^ (row & 7);
          af[mi][ks] = *(const s16x8*)&la[row * 64 + u * 8];
        }
      __builtin_amdgcn_s_setprio(1);
#pragma unroll
      for (int mi = 0; mi < 2; ++mi)
#pragma unroll
        for (int ni = 0; ni < 4; ++ni)
#pragma unroll
          for (int ks = 0; ks < 2; ++ks)
            acc[p * 2 + mi][ni] = mfma_bf16(af[mi][ks], bfr[ni][ks], acc[p * 2 + mi][ni]);
      __builtin_amdgcn_s_setprio(0);
    }

    __builtin_amdgcn_s_barrier();          // all waves' reads of buf[cur] retired
    if (kt + 2 < NT) stage(cur, kt + 2);   // safe to overwrite buf[cur]
  }

#pragma unroll
  for (int mi = 0; mi < 8; ++mi)
#pragma unroll
    for (int ni = 0; ni < 4; ++ni) {
      const int row = tm + wr * 128 + mi * 16 + grp * 4;
      const int col = tn + wc * 64 + ni * 16 + lid;
#pragma unroll
      for (int j = 0; j < 4; ++j) {
        if constexpr (BF16OUT)
          ((unsigned short*)Cv)[(size_t)(row + j) * N + col] = f2bf(acc[mi][ni][j]);
        else
          ((float*)Cv)[(size_t)(row + j) * N + col] = acc[mi][ni][j];
      }
    }
}

// ---------- causal flash attention ----------
// 32x32 MFMA, QBLK=32/wave, KVBLK=64, 4 waves/block.
// Triangle pairing: block jx handles q-tiles {15-jx, jx} -> constant 34 steps/block.
// Double-buffered K/V staging; V ds_writes after compute (T14 split). One barrier/step.
// S^T = mfma32(K,Q); O^T = mfma32(V^T, P). Q pre-scaled by hd^-0.5*log2(e).
__global__ __launch_bounds__(256, 2) void attn_kernel(const unsigned short* __restrict__ Q,
                                                      const unsigned short* __restrict__ Kg,
                                                      const unsigned short* __restrict__ Vg,
                                                      unsigned short* __restrict__ O) {
  const int D = 2048, T = 2048;
  __shared__ unsigned short lK[2][64 * 128];   // XOR-swizzled: unit u stores logical u^(row&7)
  __shared__ unsigned short lVT[2][128 * 64];  // V^T, unit u' = u ^ ((d&7)^((d>>3)&7))

  const int tid = threadIdx.x, w = tid >> 6, lane = tid & 63;
  const int lam = lane & 31, H = lane >> 5;
  const int jx = blockIdx.x;
  const int b = blockIdx.y >> 4, h = blockIdx.y & 15;
  const size_t base = (size_t)b * T * D + (size_t)h * 128;
  const unsigned short* Qp = Q + base;
  const unsigned short* Kp = Kg + base;
  const unsigned short* Vp = Vg + base;

  fx16 zf;
#pragma unroll
  for (int i = 0; i < 16; ++i) zf[i] = 0.f;

  s16x8 va[2], vb[2];   // in-flight V stage regs

  for (int pass = 0; pass < 2; ++pass) {
    const int qt = (pass == 0) ? (15 - jx) : jx;
    const int qb = qt * 128;
    const int q0 = qb + w * 32;
    const int q = q0 + lam;
    const int nsteps = qt * 2 + 2;

    s16x8 qf[8];
    {
      const unsigned short* qrow = Qp + (size_t)q * D + H * 8;
#pragma unroll
      for (int s = 0; s < 8; ++s) qf[s] = *(const s16x8*)(qrow + s * 16);
    }

    fx16 o[4] = {zf, zf, zf, zf};
    float mrun = -1e30f, lrun = 0.f;

    auto vloadV = [&](int kt0) {
#pragma unroll
      for (int t = 0; t < 2; ++t) {
        int idx = t * 256 + tid;
        int p = idx >> 4, d8 = idx & 15;
        const unsigned short* vp = Vp + (size_t)(kt0 + p * 2) * D + d8 * 8;
        va[t] = *(const s16x8*)vp;
        vb[t] = *(const s16x8*)(vp + D);
      }
    };
    auto vwriteV = [&](int bsel) {
#pragma unroll
      for (int t = 0; t < 2; ++t) {
        int idx = t * 256 + tid;
        int p = idx >> 4, d8 = idx & 15;
#pragma unroll
        for (int j = 0; j < 8; ++j) {
          int d = d8 * 8 + j;
          int up = (p >> 2) ^ j ^ (d8 & 7);     // u ^ f(d), f(d)=(d&7)^((d>>3)&7)
          unsigned int word = (unsigned int)(unsigned short)va[t][j] |
                              ((unsigned int)(unsigned short)vb[t][j] << 16);
          *(unsigned int*)&lVT[bsel][d * 64 + up * 8 + (p & 3) * 2] = word;
        }
      }
    };
    auto stageK = [&](int bsel, int kt0) {
#pragma unroll
      for (int i = 0; i < 4; ++i) {
        int c = i * 256 + tid;
        int row = c >> 4, u = c & 15;
        int su = u ^ (row & 7);
        glds16(Kp + (size_t)(kt0 + row) * D + su * 8, &lK[bsel][(i * 256 + w * 64) * 8]);
      }
    };

    vloadV(0);
    stageK(0, 0);
    vwriteV(0);
    __syncthreads();

    for (int s = 0; s < nsteps; ++s) {
      const int kt0 = s << 6;
      const int cur = s & 1, nxt = cur ^ 1;

      if (s + 1 < nsteps) {
        vloadV((s + 1) << 6);
        stageK(nxt, (s + 1) << 6);
      }

      if (kt0 <= q0 + 31) {
        // ---- S^T = mfma32(K, Q)
        fx16 st0 = zf, st1 = zf;
#pragma unroll
        for (int ss = 0; ss < 8; ++ss) {
          int uoff = ((2 * ss + H) ^ (lam & 7)) * 8;
          s16x8 k0 = *(const s16x8*)&lK[cur][lam * 128 + uoff];
          s16x8 k1 = *(const s16x8*)&lK[cur][(32 + lam) * 128 + uoff];
          st0 = mfma32(k0, qf[ss], st0);
          st1 = mfma32(k1, qf[ss], st1);
        }

        // ---- causal mask
        if (kt0 + 63 > q0) {
          const int kb = kt0 + 4 * H;
#pragma unroll
          for (int r = 0; r < 16; ++r) {
            int kv = kb + (r & 3) + 8 * (r >> 2);
            if (kv > q) st0[r] = -1e30f;
            if (kv + 32 > q) st1[r] = -1e30f;
          }
        }

        // ---- online softmax (exp2 domain), T13 defer-max; max3-fusable chains
        float pa = fmaxf(st0[0], st0[1]);
        float pb = fmaxf(st0[2], st0[3]);
#pragma unroll
        for (int r = 4; r < 16; r += 4) {
          pa = fmaxf(fmaxf(pa, st0[r]), st0[r + 1]);
          pb = fmaxf(fmaxf(pb, st0[r + 2]), st0[r + 3]);
        }
#pragma unroll
        for (int r = 0; r < 16; r += 4) {
          pa = fmaxf(fmaxf(pa, st1[r]), st1[r + 1]);
          pb = fmaxf(fmaxf(pb, st1[r + 2]), st1[r + 3]);
        }
        float pmax = fmaxf(pa, pb);
        pmax = fmaxf(pmax, __shfl_xor(pmax, 32, 64));
        if (!__all(pmax <= mrun + 12.f)) {
          float mnew = fmaxf(mrun, pmax);
          float al = exp2f(mrun - mnew);
          mrun = mnew;
          lrun *= al;
#pragma unroll
          for (int r = 0; r < 16; ++r) {
            o[0][r] *= al; o[1][r] *= al; o[2][r] *= al; o[3][r] *= al;
          }
        }
        float lloc = 0.f;
#pragma unroll
        for (int r = 0; r < 16; ++r) { st0[r] = exp2f(st0[r] - mrun); lloc += st0[r]; }
#pragma unroll
        for (int r = 0; r < 16; ++r) { st1[r] = exp2f(st1[r] - mrun); lloc += st1[r]; }
        lrun += lloc;

        // ---- pack P to bf16 pair-words (v_cvt_pk), exchange halves
        unsigned int w0[8], w1[8], w0s[8], w1s[8];
#pragma unroll
        for (int m = 0; m < 8; ++m) {
          w0[m] = cvtpk(st0[2 * m], st0[2 * m + 1]);
          w1[m] = cvtpk(st1[2 * m], st1[2 * m + 1]);
        }
#pragma unroll
        for (int m = 0; m < 8; ++m) {
          w0s[m] = __shfl_xor(w0[m], 32, 64);
          w1s[m] = __shfl_xor(w1[m], 32, 64);
        }

        // ---- PV: O^T += mfma32(V^T_frag, P_frag)
        const bool Hi = (H != 0);
#pragma unroll
        for (int c = 0; c < 4; ++c) {
          union { s16x8 v; unsigned int u[4]; } pbu;
          if (c < 2) {
            const int a = 4 * (c & 1);
            pbu.u[0] = Hi ? w0s[a + 2] : w0[a + 0];
            pbu.u[1] = Hi ? w0s[a + 3] : w0[a + 1];
            pbu.u[2] = Hi ? w0[a + 2] : w0s[a + 0];
            pbu.u[3] = Hi ? w0[a + 3] : w0s[a + 1];
          } else {
            const int a = 4 * (c & 1);
            pbu.u[0] = Hi ? w1s[a + 2] : w1[a + 0];
            pbu.u[1] = Hi ? w1s[a + 3] : w1[a + 1];
            pbu.u[2] = Hi ? w1[a + 2] : w1s[a + 0];
            pbu.u[3] = Hi ? w1[a + 3] : w1s[a + 1];
          }
#pragma unroll
          for (int dt = 0; dt < 4; ++dt) {
            int d = dt * 32 + lam;
            int fd = (lam & 7) ^ ((dt * 4 + (lam >> 3)) & 7);
            s16x8 vf = *(const s16x8*)&lVT[cur][d * 64 + ((2 * c + H) ^ fd) * 8];
            o[dt] = mfma32(vf, pbu.v, o[dt]);
          }
        }
      }

      if (s + 1 < nsteps) vwriteV(nxt);
      __syncthreads();
    }

    // ---- epilogue
    lrun += __shfl_xor(lrun, 32, 64);
    float inv = 1.f / lrun;
    unsigned short* orow = O + base + (size_t)q * D;
#pragma unroll
    for (int dt = 0; dt < 4; ++dt)
#pragma unroll
      for (int rq = 0; rq < 4; ++rq) {
        u32x2 uv;
        uv[0] = cvtpk(o[dt][rq * 4 + 0] * inv, o[dt][rq * 4 + 1] * inv);
        uv[1] = cvtpk(o[dt][rq * 4 + 2] * inv, o[dt][rq * 4 + 3] * inv);
        *(u32x2*)(orow + dt * 32 + rq * 8 + H * 4) = uv;
      }
  }
}

// ---------- launch ----------
extern "C" void kernel_launch(void* const* d_in, const int* in_sizes, int n_in,
                              void* d_out, int out_size, void* d_ws, size_t ws_size,
                              hipStream_t stream) {
  (void)in_sizes; (void)n_in; (void)out_size; (void)ws_size;
  const float* x  = (const float*)d_in[0];
  const float* Wq = (const float*)d_in[1];
  const float* Wk = (const float*)d_in[2];
  const float* Wv = (const float*)d_in[3];
  const float* Wo = (const float*)d_in[4];
  const float* gq = (const float*)d_in[5];
  const float* gk = (const float*)d_in[6];
  float* out = (float*)d_out;

  // workspace layout (bytes): peak 136 MB
  char* W = (char*)d_ws;
  unsigned short* xb    = (unsigned short*)(W);                       // 32 MB  x bf16 (later reused for attn out)
  unsigned short* wslot = (unsigned short*)(W + (size_t)33554432);    //  8 MB  current weight bf16
  unsigned short* Qb    = (unsigned short*)(W + (size_t)41943040);    // 32 MB
  unsigned short* Kb    = (unsigned short*)(W + (size_t)75497472);    // 32 MB
  unsigned short* Vb    = (unsigned short*)(W + (size_t)109051904);   // 32 MB
  unsigned short* AO    = xb;                                         // attn out reuses x region

  const dim3 gg(8, 32);   // N/256, M/256

  cvt_kernel<<<4096, 256, 0, stream>>>(x, xb, 16777216);

  cvt_kernel<<<4096, 256, 0, stream>>>(Wq, wslot, 4194304);
  gemm256<true><<<gg, 512, 0, stream>>>(xb, wslot, Qb, 8192, 2048, 2048);
  cvt_kernel<<<4096, 256, 0, stream>>>(Wk, wslot, 4194304);
  gemm256<true><<<gg, 512, 0, stream>>>(xb, wslot, Kb, 8192, 2048, 2048);
  cvt_kernel<<<4096, 256, 0, stream>>>(Wv, wslot, 4194304);
  gemm256<true><<<gg, 512, 0, stream>>>(xb, wslot, Vb, 8192, 2048, 2048);

  // fold hd^-0.5 * log2(e) into Q (softmax runs in exp2 domain)
  rms_kernel<<<8192, 256, 0, stream>>>(Qb, gq, (float)(0.08838834764831845 * 1.4426950408889634));
  rms_kernel<<<8192, 256, 0, stream>>>(Kb, gk, 1.0f);

  attn_kernel<<<dim3(8, 64), 256, 0, stream>>>(Qb, Kb, Vb, AO);

  cvt_kernel<<<4096, 256, 0, stream>>>(Wo, wslot, 4194304);
  gemm256<false><<<gg, 512, 0, stream>>>(AO, wslot, out, 8192, 2048, 2048);
}

// Round 6
// 449.700 us; speedup vs baseline: 1.5164x; 1.0853x over previous
//
#include <hip/hip_runtime.h>

// ---------- types ----------
typedef short  s16x8 __attribute__((ext_vector_type(8)));
typedef __bf16 bf16x8 __attribute__((ext_vector_type(8)));
typedef float  fx4   __attribute__((ext_vector_type(4)));
typedef float  fx16  __attribute__((ext_vector_type(16)));
typedef unsigned short u16x4 __attribute__((ext_vector_type(4)));
typedef unsigned int   u32x2 __attribute__((ext_vector_type(2)));
typedef unsigned int   u32x4 __attribute__((ext_vector_type(4)));

__device__ __forceinline__ fx4 mfma_bf16(s16x8 a, s16x8 b, fx4 c) {
  return __builtin_amdgcn_mfma_f32_16x16x32_bf16(
      __builtin_bit_cast(bf16x8, a), __builtin_bit_cast(bf16x8, b), c, 0, 0, 0);
}

__device__ __forceinline__ fx16 mfma32(s16x8 a, s16x8 b, fx16 c) {
  return __builtin_amdgcn_mfma_f32_32x32x16_bf16(
      __builtin_bit_cast(bf16x8, a), __builtin_bit_cast(bf16x8, b), c, 0, 0, 0);
}

__device__ __forceinline__ unsigned short f2bf(float f) {
  unsigned int u = __float_as_uint(f);
  u += 0x7fffu + ((u >> 16) & 1u);   // RNE
  return (unsigned short)(u >> 16);
}

__device__ __forceinline__ float bf2f(unsigned int bits16) {
  return __uint_as_float(bits16 << 16);
}

// packed f32x2 -> bf16x2 (RNE), T12 primitive (no builtin on gfx950)
__device__ __forceinline__ unsigned int cvtpk(float lo, float hi) {
  unsigned int r;
  asm volatile("v_cvt_pk_bf16_f32 %0, %1, %2" : "=v"(r) : "v"(lo), "v"(hi));
  return r;
}

// global -> LDS direct copy, 16B per lane; LDS dest = wave-uniform base + lane*16
__device__ __forceinline__ void glds16(const void* g, void* l) {
  __builtin_amdgcn_global_load_lds(
      (__attribute__((address_space(1))) unsigned int*)g,
      (__attribute__((address_space(3))) unsigned int*)l, 16, 0, 0);
}

// ---------- fp32 -> bf16 conversion ----------
__global__ __launch_bounds__(256) void cvt_kernel(const float* __restrict__ src,
                                                  unsigned short* __restrict__ dst, int n) {
  int nv = n >> 2;
  for (int i = blockIdx.x * blockDim.x + threadIdx.x; i < nv; i += gridDim.x * blockDim.x) {
    fx4 v = ((const fx4*)src)[i];
    u16x4 o;
#pragma unroll
    for (int j = 0; j < 4; ++j) o[j] = f2bf(v[j]);
    ((u16x4*)dst)[i] = o;
  }
}

// ---------- GEMM: C[M,N] = A[M,K] * B[N,K]^T ----------
// 256x256 tile, BK=64, 8 waves (2m x 4n), dbuf LDS 128 KiB, XOR-swizzled units.
// m201-style 4-phase cadence per K-tile:
//   phase p: {ds_read af (4 b128; phase 0 also bfr 8) | issue 2 glds | barrier |
//             setprio(1) 16 MFMA setprio(0) | barrier}
// Staging plan (proven race-free by consumption order):
//   p0: A rows{64..127,192..255} of tile kt+1 -> slot cur^1 (those rows of cur^1
//       were consumed at tile kt-1 phases 2/3)
//   p1: B rows{0..127}   of tile kt+2 -> slot cur (B fully reg-buffered at p0)
//   p2: B rows{128..255} of tile kt+2 -> slot cur
//   p3: A rows{0..63,128..191} of kt+2 -> slot cur (consumed at p0/p1) + vmcnt(6)
// vmcnt(6) at p3: the 6 newest outstanding are kt+2's stages -> tile kt+1 fully
// landed before its phase-0 reads. Never drains to 0 mid-loop (T4).
// OMODE: 0 = f32 out, 1 = bf16 out, 2 = bf16 + per-head RMSNorm (head_dim=128)
template <int OMODE>
__global__ __launch_bounds__(512, 2) void gemm256(const unsigned short* __restrict__ A,
                                                  const unsigned short* __restrict__ B,
                                                  void* __restrict__ Cv,
                                                  const float* __restrict__ g,
                                                  float postscale,
                                                  int M, int N, int K) {
  __shared__ unsigned short lA[2][256 * 64];
  __shared__ unsigned short lB[2][256 * 64];
  const int tid = threadIdx.x, w = tid >> 6, lane = tid & 63;
  const int lid = lane & 15, grp = lane >> 4;
  const int wr = w >> 2, wc = w & 3;
  const int tm = blockIdx.y * 256, tn = blockIdx.x * 256;

  auto stageA = [&](int buf, int kt, int ia, int ib) {
    const int k0 = kt * 64;
#pragma unroll
    for (int t = 0; t < 2; ++t) {
      int i = t ? ib : ia;
      int c = i * 512 + tid;
      int row = c >> 3, u = c & 7;
      int su = u ^ (row & 7);
      glds16(A + (size_t)(tm + row) * K + k0 + su * 8, &lA[buf][(i * 512 + w * 64) * 8]);
    }
  };
  auto stageB = [&](int buf, int kt, int ia, int ib) {
    const int k0 = kt * 64;
#pragma unroll
    for (int t = 0; t < 2; ++t) {
      int i = t ? ib : ia;
      int c = i * 512 + tid;
      int row = c >> 3, u = c & 7;
      int su = u ^ (row & 7);
      glds16(B + (size_t)(tn + row) * K + k0 + su * 8, &lB[buf][(i * 512 + w * 64) * 8]);
    }
  };

  fx4 acc[8][4];
#pragma unroll
  for (int i = 0; i < 8; ++i)
#pragma unroll
    for (int j = 0; j < 4; ++j) acc[i][j] = fx4{0.f, 0.f, 0.f, 0.f};

  // prologue: tile0 full -> slot0; tile1 B + A{0,2} -> slot1 (A{1,3} issued at kt0.p0)
  stageA(0, 0, 0, 1); stageA(0, 0, 2, 3);
  stageB(0, 0, 0, 1); stageB(0, 0, 2, 3);
  stageB(1, 1, 0, 1); stageB(1, 1, 2, 3);
  stageA(1, 1, 0, 2);
  asm volatile("s_waitcnt vmcnt(6)" ::: "memory");   // tile0's 8 landed
  __builtin_amdgcn_s_barrier();
  __builtin_amdgcn_sched_barrier(0);

#define BARX { __builtin_amdgcn_s_barrier(); __builtin_amdgcn_sched_barrier(0); }
#define LDAF(P)                                                               \
  s16x8 af##P[2][2];                                                          \
  _Pragma("unroll") for (int mi = 0; mi < 2; ++mi)                            \
  _Pragma("unroll") for (int ks = 0; ks < 2; ++ks) {                          \
    int row = wr * 128 + ((P) * 2 + mi) * 16 + lid;                           \
    int u = (ks * 4 + grp) ^ (row & 7);                                       \
    af##P[mi][ks] = *(const s16x8*)&la[row * 64 + u * 8];                     \
  }
#define MFMAG(P)                                                              \
  __builtin_amdgcn_s_setprio(1);                                              \
  _Pragma("unroll") for (int mi = 0; mi < 2; ++mi)                            \
  _Pragma("unroll") for (int ni = 0; ni < 4; ++ni)                            \
  _Pragma("unroll") for (int ks = 0; ks < 2; ++ks)                            \
    acc[(P) * 2 + mi][ni] =                                                   \
        mfma_bf16(af##P[mi][ks], bfr[ni][ks], acc[(P) * 2 + mi][ni]);         \
  __builtin_amdgcn_s_setprio(0);

  const int NT = K >> 6;
  for (int kt = 0; kt < NT; ++kt) {
    const int cur = kt & 1;
    const unsigned short* la = &lA[cur][0];
    const unsigned short* lb = &lB[cur][0];

    // ---- phase 0: bfr (whole tile's B) + af0; stage A{1,3} of kt+1
    s16x8 bfr[4][2];
#pragma unroll
    for (int ni = 0; ni < 4; ++ni)
#pragma unroll
      for (int ks = 0; ks < 2; ++ks) {
        int row = wc * 64 + ni * 16 + lid;
        int u = (ks * 4 + grp) ^ (row & 7);
        bfr[ni][ks] = *(const s16x8*)&lb[row * 64 + u * 8];
      }
    LDAF(0)
    if (kt + 1 < NT) stageA(cur ^ 1, kt + 1, 1, 3);
    BARX
    MFMAG(0)
    BARX
    // ---- phase 1
    LDAF(1)
    if (kt + 2 < NT) stageB(cur, kt + 2, 0, 1);
    BARX
    MFMAG(1)
    BARX
    // ---- phase 2
    LDAF(2)
    if (kt + 2 < NT) stageB(cur, kt + 2, 2, 3);
    BARX
    MFMAG(2)
    BARX
    // ---- phase 3 (+ counted vmcnt once per tile)
    LDAF(3)
    if (kt + 2 < NT) {
      stageA(cur, kt + 2, 0, 2);
      asm volatile("s_waitcnt vmcnt(6)" ::: "memory");
    } else {
      asm volatile("s_waitcnt vmcnt(0)" ::: "memory");
    }
    BARX
    MFMAG(3)
    BARX
  }
#undef LDAF
#undef MFMAG
#undef BARX

  float rinv[8][4];
  if constexpr (OMODE == 2) {
    // per-row sum of squares over the 128-col head segment (2 waves: wc pairs)
    float* lS = (float*)&lA[0][0];
    float red[8][4];
#pragma unroll
    for (int mi = 0; mi < 8; ++mi)
#pragma unroll
      for (int j = 0; j < 4; ++j) {
        float s = 0.f;
#pragma unroll
        for (int ni = 0; ni < 4; ++ni) { float v = acc[mi][ni][j]; s += v * v; }
#pragma unroll
        for (int m = 1; m <= 8; m <<= 1) s += __shfl_xor(s, m, 64);
        red[mi][j] = s;
      }
    if (lid == 0) {
#pragma unroll
      for (int mi = 0; mi < 8; ++mi)
#pragma unroll
        for (int j = 0; j < 4; ++j)
          lS[w * 128 + mi * 16 + grp * 4 + j] = red[mi][j];
    }
    __syncthreads();
#pragma unroll
    for (int mi = 0; mi < 8; ++mi)
#pragma unroll
      for (int j = 0; j < 4; ++j) {
        float tot = red[mi][j] + lS[(w ^ 1) * 128 + mi * 16 + grp * 4 + j];
        rinv[mi][j] = rsqrtf(tot * (1.0f / 128.0f) + 1e-5f) * postscale;
      }
#pragma unroll
    for (int ni = 0; ni < 4; ++ni) {
      float gv = g[(wc & 1) * 64 + ni * 16 + lid];
#pragma unroll
      for (int mi = 0; mi < 8; ++mi)
#pragma unroll
        for (int j = 0; j < 4; ++j)
          acc[mi][ni][j] *= rinv[mi][j] * gv;
    }
  }

#pragma unroll
  for (int mi = 0; mi < 8; ++mi)
#pragma unroll
    for (int ni = 0; ni < 4; ++ni) {
      const int row = tm + wr * 128 + mi * 16 + grp * 4;
      const int col = tn + wc * 64 + ni * 16 + lid;
#pragma unroll
      for (int j = 0; j < 4; ++j) {
        if constexpr (OMODE >= 1)
          ((unsigned short*)Cv)[(size_t)(row + j) * N + col] = f2bf(acc[mi][ni][j]);
        else
          ((float*)Cv)[(size_t)(row + j) * N + col] = acc[mi][ni][j];
      }
    }
}

// ---------- causal flash attention ----------
// 32x32 MFMA, QBLK=32/wave, KVBLK=64, 4 waves/block.
// Triangle pairing: block jx handles q-tiles {15-jx, jx} -> constant 34 steps/block.
// Double-buffered K/V staging; V ds_writes after compute (T14 split). One barrier/step.
// S^T = mfma32(K,Q); O^T = mfma32(V^T, P). Q pre-scaled by hd^-0.5*log2(e).
__global__ __launch_bounds__(256, 2) void attn_kernel(const unsigned short* __restrict__ Q,
                                                      const unsigned short* __restrict__ Kg,
                                                      const unsigned short* __restrict__ Vg,
                                                      unsigned short* __restrict__ O) {
  const int D = 2048, T = 2048;
  __shared__ unsigned short lK[2][64 * 128];   // XOR-swizzled: unit u stores logical u^(row&7)
  __shared__ unsigned short lVT[2][128 * 64];  // V^T, unit u' = u ^ ((d&7)^((d>>3)&7))

  const int tid = threadIdx.x, w = tid >> 6, lane = tid & 63;
  const int lam = lane & 31, H = lane >> 5;
  const int jx = blockIdx.x;
  const int b = blockIdx.y >> 4, h = blockIdx.y & 15;
  const size_t base = (size_t)b * T * D + (size_t)h * 128;
  const unsigned short* Qp = Q + base;
  const unsigned short* Kp = Kg + base;
  const unsigned short* Vp = Vg + base;

  fx16 zf;
#pragma unroll
  for (int i = 0; i < 16; ++i) zf[i] = 0.f;

  s16x8 va[2], vb[2];   // in-flight V stage regs

  for (int pass = 0; pass < 2; ++pass) {
    const int qt = (pass == 0) ? (15 - jx) : jx;
    const int qb = qt * 128;
    const int q0 = qb + w * 32;
    const int q = q0 + lam;
    const int nsteps = qt * 2 + 2;

    s16x8 qf[8];
    {
      const unsigned short* qrow = Qp + (size_t)q * D + H * 8;
#pragma unroll
      for (int s = 0; s < 8; ++s) qf[s] = *(const s16x8*)(qrow + s * 16);
    }

    fx16 o[4] = {zf, zf, zf, zf};
    float mrun = -1e30f, lrun = 0.f;

    auto vloadV = [&](int kt0) {
#pragma unroll
      for (int t = 0; t < 2; ++t) {
        int idx = t * 256 + tid;
        int p = idx >> 4, d8 = idx & 15;
        const unsigned short* vp = Vp + (size_t)(kt0 + p * 2) * D + d8 * 8;
        va[t] = *(const s16x8*)vp;
        vb[t] = *(const s16x8*)(vp + D);
      }
    };
    auto vwriteV = [&](int bsel) {
#pragma unroll
      for (int t = 0; t < 2; ++t) {
        int idx = t * 256 + tid;
        int p = idx >> 4, d8 = idx & 15;
#pragma unroll
        for (int j = 0; j < 8; ++j) {
          int d = d8 * 8 + j;
          int up = (p >> 2) ^ j ^ (d8 & 7);     // u ^ f(d), f(d)=(d&7)^((d>>3)&7)
          unsigned int word = (unsigned int)(unsigned short)va[t][j] |
                              ((unsigned int)(unsigned short)vb[t][j] << 16);
          *(unsigned int*)&lVT[bsel][d * 64 + up * 8 + (p & 3) * 2] = word;
        }
      }
    };
    auto stageK = [&](int bsel, int kt0) {
#pragma unroll
      for (int i = 0; i < 4; ++i) {
        int c = i * 256 + tid;
        int row = c >> 4, u = c & 15;
        int su = u ^ (row & 7);
        glds16(Kp + (size_t)(kt0 + row) * D + su * 8, &lK[bsel][(i * 256 + w * 64) * 8]);
      }
    };

    vloadV(0);
    stageK(0, 0);
    vwriteV(0);
    __syncthreads();

    for (int s = 0; s < nsteps; ++s) {
      const int kt0 = s << 6;
      const int cur = s & 1, nxt = cur ^ 1;

      if (s + 1 < nsteps) {
        vloadV((s + 1) << 6);
        stageK(nxt, (s + 1) << 6);
      }

      if (kt0 <= q0 + 31) {
        // ---- S^T = mfma32(K, Q)
        fx16 st0 = zf, st1 = zf;
#pragma unroll
        for (int ss = 0; ss < 8; ++ss) {
          int uoff = ((2 * ss + H) ^ (lam & 7)) * 8;
          s16x8 k0 = *(const s16x8*)&lK[cur][lam * 128 + uoff];
          s16x8 k1 = *(const s16x8*)&lK[cur][(32 + lam) * 128 + uoff];
          st0 = mfma32(k0, qf[ss], st0);
          st1 = mfma32(k1, qf[ss], st1);
        }

        // ---- causal mask
        if (kt0 + 63 > q0) {
          const int kb = kt0 + 4 * H;
#pragma unroll
          for (int r = 0; r < 16; ++r) {
            int kv = kb + (r & 3) + 8 * (r >> 2);
            if (kv > q) st0[r] = -1e30f;
            if (kv + 32 > q) st1[r] = -1e30f;
          }
        }

        // ---- online softmax (exp2 domain), T13 defer-max; max3-fusable chains
        float pa = fmaxf(st0[0], st0[1]);
        float pb = fmaxf(st0[2], st0[3]);
#pragma unroll
        for (int r = 4; r < 16; r += 4) {
          pa = fmaxf(fmaxf(pa, st0[r]), st0[r + 1]);
          pb = fmaxf(fmaxf(pb, st0[r + 2]), st0[r + 3]);
        }
#pragma unroll
        for (int r = 0; r < 16; r += 4) {
          pa = fmaxf(fmaxf(pa, st1[r]), st1[r + 1]);
          pb = fmaxf(fmaxf(pb, st1[r + 2]), st1[r + 3]);
        }
        float pmax = fmaxf(pa, pb);
        pmax = fmaxf(pmax, __shfl_xor(pmax, 32, 64));
        if (!__all(pmax <= mrun + 12.f)) {
          float mnew = fmaxf(mrun, pmax);
          float al = exp2f(mrun - mnew);
          mrun = mnew;
          lrun *= al;
#pragma unroll
          for (int r = 0; r < 16; ++r) {
            o[0][r] *= al; o[1][r] *= al; o[2][r] *= al; o[3][r] *= al;
          }
        }
        float lloc = 0.f;
#pragma unroll
        for (int r = 0; r < 16; ++r) { st0[r] = exp2f(st0[r] - mrun); lloc += st0[r]; }
#pragma unroll
        for (int r = 0; r < 16; ++r) { st1[r] = exp2f(st1[r] - mrun); lloc += st1[r]; }
        lrun += lloc;

        // ---- pack P to bf16 pair-words (v_cvt_pk), exchange halves
        unsigned int w0[8], w1[8], w0s[8], w1s[8];
#pragma unroll
        for (int m = 0; m < 8; ++m) {
          w0[m] = cvtpk(st0[2 * m], st0[2 * m + 1]);
          w1[m] = cvtpk(st1[2 * m], st1[2 * m + 1]);
        }
#pragma unroll
        for (int m = 0; m < 8; ++m) {
          w0s[m] = __shfl_xor(w0[m], 32, 64);
          w1s[m] = __shfl_xor(w1[m], 32, 64);
        }

        // ---- PV: O^T += mfma32(V^T_frag, P_frag)
        const bool Hi = (H != 0);
#pragma unroll
        for (int c = 0; c < 4; ++c) {
          union { s16x8 v; unsigned int u[4]; } pbu;
          if (c < 2) {
            const int a = 4 * (c & 1);
            pbu.u[0] = Hi ? w0s[a + 2] : w0[a + 0];
            pbu.u[1] = Hi ? w0s[a + 3] : w0[a + 1];
            pbu.u[2] = Hi ? w0[a + 2] : w0s[a + 0];
            pbu.u[3] = Hi ? w0[a + 3] : w0s[a + 1];
          } else {
            const int a = 4 * (c & 1);
            pbu.u[0] = Hi ? w1s[a + 2] : w1[a + 0];
            pbu.u[1] = Hi ? w1s[a + 3] : w1[a + 1];
            pbu.u[2] = Hi ? w1[a + 2] : w1s[a + 0];
            pbu.u[3] = Hi ? w1[a + 3] : w1s[a + 1];
          }
#pragma unroll
          for (int dt = 0; dt < 4; ++dt) {
            int d = dt * 32 + lam;
            int fd = (lam & 7) ^ ((dt * 4 + (lam >> 3)) & 7);
            s16x8 vf = *(const s16x8*)&lVT[cur][d * 64 + ((2 * c + H) ^ fd) * 8];
            o[dt] = mfma32(vf, pbu.v, o[dt]);
          }
        }
      }

      if (s + 1 < nsteps) vwriteV(nxt);
      __syncthreads();
    }

    // ---- epilogue
    lrun += __shfl_xor(lrun, 32, 64);
    float inv = 1.f / lrun;
    unsigned short* orow = O + base + (size_t)q * D;
#pragma unroll
    for (int dt = 0; dt < 4; ++dt)
#pragma unroll
      for (int rq = 0; rq < 4; ++rq) {
        u32x2 uv;
        uv[0] = cvtpk(o[dt][rq * 4 + 0] * inv, o[dt][rq * 4 + 1] * inv);
        uv[1] = cvtpk(o[dt][rq * 4 + 2] * inv, o[dt][rq * 4 + 3] * inv);
        *(u32x2*)(orow + dt * 32 + rq * 8 + H * 4) = uv;
      }
  }
}

// ---------- launch ----------
extern "C" void kernel_launch(void* const* d_in, const int* in_sizes, int n_in,
                              void* d_out, int out_size, void* d_ws, size_t ws_size,
                              hipStream_t stream) {
  (void)in_sizes; (void)n_in; (void)out_size; (void)ws_size;
  const float* x  = (const float*)d_in[0];
  const float* Wq = (const float*)d_in[1];
  const float* Wk = (const float*)d_in[2];
  const float* Wv = (const float*)d_in[3];
  const float* Wo = (const float*)d_in[4];
  const float* gq = (const float*)d_in[5];
  const float* gk = (const float*)d_in[6];
  float* out = (float*)d_out;

  // workspace layout (bytes): peak 136 MB
  char* W = (char*)d_ws;
  unsigned short* xb    = (unsigned short*)(W);                       // 32 MB  x bf16 (later reused for attn out)
  unsigned short* wslot = (unsigned short*)(W + (size_t)33554432);    //  8 MB  current weight bf16
  unsigned short* Qb    = (unsigned short*)(W + (size_t)41943040);    // 32 MB
  unsigned short* Kb    = (unsigned short*)(W + (size_t)75497472);    // 32 MB
  unsigned short* Vb    = (unsigned short*)(W + (size_t)109051904);   // 32 MB
  unsigned short* AO    = xb;                                         // attn out reuses x region

  const dim3 gg(8, 32);   // N/256, M/256
  const float qscale = (float)(0.08838834764831845 * 1.4426950408889634); // hd^-0.5 * log2(e)

  cvt_kernel<<<4096, 256, 0, stream>>>(x, xb, 16777216);

  cvt_kernel<<<4096, 256, 0, stream>>>(Wq, wslot, 4194304);
  gemm256<2><<<gg, 512, 0, stream>>>(xb, wslot, Qb, gq, qscale, 8192, 2048, 2048);
  cvt_kernel<<<4096, 256, 0, stream>>>(Wk, wslot, 4194304);
  gemm256<2><<<gg, 512, 0, stream>>>(xb, wslot, Kb, gk, 1.0f, 8192, 2048, 2048);
  cvt_kernel<<<4096, 256, 0, stream>>>(Wv, wslot, 4194304);
  gemm256<1><<<gg, 512, 0, stream>>>(xb, wslot, Vb, gq, 1.0f, 8192, 2048, 2048);

  attn_kernel<<<dim3(8, 64), 256, 0, stream>>>(Qb, Kb, Vb, AO);

  cvt_kernel<<<4096, 256, 0, stream>>>(Wo, wslot, 4194304);
  gemm256<0><<<gg, 512, 0, stream>>>(AO, wslot, out, gq, 1.0f, 8192, 2048, 2048);
}

// Round 7
// 428.634 us; speedup vs baseline: 1.5909x; 1.0491x over previous
//
#include <hip/hip_runtime.h>

// ---------- types ----------
typedef short  s16x8 __attribute__((ext_vector_type(8)));
typedef __bf16 bf16x8 __attribute__((ext_vector_type(8)));
typedef float  fx4   __attribute__((ext_vector_type(4)));
typedef float  fx16  __attribute__((ext_vector_type(16)));
typedef unsigned short u16x4 __attribute__((ext_vector_type(4)));
typedef unsigned int   u32x2 __attribute__((ext_vector_type(2)));
typedef unsigned int   u32x4 __attribute__((ext_vector_type(4)));

__device__ __forceinline__ fx4 mfma_bf16(s16x8 a, s16x8 b, fx4 c) {
  return __builtin_amdgcn_mfma_f32_16x16x32_bf16(
      __builtin_bit_cast(bf16x8, a), __builtin_bit_cast(bf16x8, b), c, 0, 0, 0);
}

__device__ __forceinline__ fx16 mfma32(s16x8 a, s16x8 b, fx16 c) {
  return __builtin_amdgcn_mfma_f32_32x32x16_bf16(
      __builtin_bit_cast(bf16x8, a), __builtin_bit_cast(bf16x8, b), c, 0, 0, 0);
}

__device__ __forceinline__ unsigned short f2bf(float f) {
  unsigned int u = __float_as_uint(f);
  u += 0x7fffu + ((u >> 16) & 1u);   // RNE
  return (unsigned short)(u >> 16);
}

__device__ __forceinline__ float bf2f(unsigned int bits16) {
  return __uint_as_float(bits16 << 16);
}

// packed f32x2 -> bf16x2 (RNE), T12 primitive (no builtin on gfx950)
__device__ __forceinline__ unsigned int cvtpk(float lo, float hi) {
  unsigned int r;
  asm volatile("v_cvt_pk_bf16_f32 %0, %1, %2" : "=v"(r) : "v"(lo), "v"(hi));
  return r;
}

// global -> LDS direct copy, 16B per lane; LDS dest = wave-uniform base + lane*16
__device__ __forceinline__ void glds16(const void* g, void* l) {
  __builtin_amdgcn_global_load_lds(
      (__attribute__((address_space(1))) unsigned int*)g,
      (__attribute__((address_space(3))) unsigned int*)l, 16, 0, 0);
}

// ---------- fp32 -> bf16 conversion ----------
__global__ __launch_bounds__(256) void cvt_kernel(const float* __restrict__ src,
                                                  unsigned short* __restrict__ dst, int n) {
  int nv = n >> 2;
  for (int i = blockIdx.x * blockDim.x + threadIdx.x; i < nv; i += gridDim.x * blockDim.x) {
    fx4 v = ((const fx4*)src)[i];
    u16x4 o;
#pragma unroll
    for (int j = 0; j < 4; ++j) o[j] = f2bf(v[j]);
    ((u16x4*)dst)[i] = o;
  }
}

// ---------- GEMM: C[M,N] = A[M,K] * B[N,K]^T ----------
// 256x256 tile, BK=64, 8 waves (2m x 4n), dbuf LDS 128 KiB, XOR-swizzled units.
// m201-style 4-phase cadence per K-tile (see round-6 comments for the staging
// proof). vmcnt(6) once per K-tile, never 0 mid-loop (T4).
// T1 XCD swizzle: bijective remap so XCD x owns by in {4x..4x+3} x all bx
// (requires gridDim.x==8, gridDim.y%8==0 -- true for all our launches).
// OMODE: 0 = f32 out, 1 = bf16 out, 2 = bf16 + per-head RMSNorm (head_dim=128)
template <int OMODE>
__global__ __launch_bounds__(512, 2) void gemm256(const unsigned short* __restrict__ A,
                                                  const unsigned short* __restrict__ B,
                                                  void* __restrict__ Cv,
                                                  const float* __restrict__ g,
                                                  float postscale,
                                                  int M, int N, int K) {
  __shared__ unsigned short lA[2][256 * 64];
  __shared__ unsigned short lB[2][256 * 64];
  const int tid = threadIdx.x, w = tid >> 6, lane = tid & 63;
  const int lid = lane & 15, grp = lane >> 4;
  const int wr = w >> 2, wc = w & 3;
  // T1 XCD-aware bijective swizzle (dispatch id -> tile)
  const int lin = blockIdx.x + gridDim.x * blockIdx.y;
  const int xcd = lin & 7, idx = lin >> 3;
  const int bx = idx & 7;                              // gridDim.x == 8
  const int by = xcd * (gridDim.y >> 3) + (idx >> 3);
  const int tm = by * 256, tn = bx * 256;

  auto stageA = [&](int buf, int kt, int ia, int ib) {
    const int k0 = kt * 64;
#pragma unroll
    for (int t = 0; t < 2; ++t) {
      int i = t ? ib : ia;
      int c = i * 512 + tid;
      int row = c >> 3, u = c & 7;
      int su = u ^ (row & 7);
      glds16(A + (size_t)(tm + row) * K + k0 + su * 8, &lA[buf][(i * 512 + w * 64) * 8]);
    }
  };
  auto stageB = [&](int buf, int kt, int ia, int ib) {
    const int k0 = kt * 64;
#pragma unroll
    for (int t = 0; t < 2; ++t) {
      int i = t ? ib : ia;
      int c = i * 512 + tid;
      int row = c >> 3, u = c & 7;
      int su = u ^ (row & 7);
      glds16(B + (size_t)(tn + row) * K + k0 + su * 8, &lB[buf][(i * 512 + w * 64) * 8]);
    }
  };

  fx4 acc[8][4];
#pragma unroll
  for (int i = 0; i < 8; ++i)
#pragma unroll
    for (int j = 0; j < 4; ++j) acc[i][j] = fx4{0.f, 0.f, 0.f, 0.f};

  // prologue: tile0 full -> slot0; tile1 B + A{0,2} -> slot1 (A{1,3} issued at kt0.p0)
  stageA(0, 0, 0, 1); stageA(0, 0, 2, 3);
  stageB(0, 0, 0, 1); stageB(0, 0, 2, 3);
  stageB(1, 1, 0, 1); stageB(1, 1, 2, 3);
  stageA(1, 1, 0, 2);
  asm volatile("s_waitcnt vmcnt(6)" ::: "memory");   // tile0's 8 landed
  __builtin_amdgcn_s_barrier();
  __builtin_amdgcn_sched_barrier(0);

#define BARX { __builtin_amdgcn_s_barrier(); __builtin_amdgcn_sched_barrier(0); }
#define LDAF(P)                                                               \
  s16x8 af##P[2][2];                                                          \
  _Pragma("unroll") for (int mi = 0; mi < 2; ++mi)                            \
  _Pragma("unroll") for (int ks = 0; ks < 2; ++ks) {                          \
    int row = wr * 128 + ((P) * 2 + mi) * 16 + lid;                           \
    int u = (ks * 4 + grp) ^ (row & 7);                                       \
    af##P[mi][ks] = *(const s16x8*)&la[row * 64 + u * 8];                     \
  }
#define MFMAG(P)                                                              \
  __builtin_amdgcn_s_setprio(1);                                              \
  _Pragma("unroll") for (int mi = 0; mi < 2; ++mi)                            \
  _Pragma("unroll") for (int ni = 0; ni < 4; ++ni)                            \
  _Pragma("unroll") for (int ks = 0; ks < 2; ++ks)                            \
    acc[(P) * 2 + mi][ni] =                                                   \
        mfma_bf16(af##P[mi][ks], bfr[ni][ks], acc[(P) * 2 + mi][ni]);         \
  __builtin_amdgcn_s_setprio(0);

  const int NT = K >> 6;
  for (int kt = 0; kt < NT; ++kt) {
    const int cur = kt & 1;
    const unsigned short* la = &lA[cur][0];
    const unsigned short* lb = &lB[cur][0];

    // ---- phase 0: bfr (whole tile's B) + af0; stage A{1,3} of kt+1
    s16x8 bfr[4][2];
#pragma unroll
    for (int ni = 0; ni < 4; ++ni)
#pragma unroll
      for (int ks = 0; ks < 2; ++ks) {
        int row = wc * 64 + ni * 16 + lid;
        int u = (ks * 4 + grp) ^ (row & 7);
        bfr[ni][ks] = *(const s16x8*)&lb[row * 64 + u * 8];
      }
    LDAF(0)
    if (kt + 1 < NT) stageA(cur ^ 1, kt + 1, 1, 3);
    BARX
    MFMAG(0)
    BARX
    // ---- phase 1
    LDAF(1)
    if (kt + 2 < NT) stageB(cur, kt + 2, 0, 1);
    BARX
    MFMAG(1)
    BARX
    // ---- phase 2
    LDAF(2)
    if (kt + 2 < NT) stageB(cur, kt + 2, 2, 3);
    BARX
    MFMAG(2)
    BARX
    // ---- phase 3 (+ counted vmcnt once per tile)
    LDAF(3)
    if (kt + 2 < NT) {
      stageA(cur, kt + 2, 0, 2);
      asm volatile("s_waitcnt vmcnt(6)" ::: "memory");
    } else {
      asm volatile("s_waitcnt vmcnt(0)" ::: "memory");
    }
    BARX
    MFMAG(3)
    BARX
  }
#undef LDAF
#undef MFMAG
#undef BARX

  float rinv[8][4];
  if constexpr (OMODE == 2) {
    // per-row sum of squares over the 128-col head segment (2 waves: wc pairs)
    float* lS = (float*)&lA[0][0];
    float red[8][4];
#pragma unroll
    for (int mi = 0; mi < 8; ++mi)
#pragma unroll
      for (int j = 0; j < 4; ++j) {
        float s = 0.f;
#pragma unroll
        for (int ni = 0; ni < 4; ++ni) { float v = acc[mi][ni][j]; s += v * v; }
#pragma unroll
        for (int m = 1; m <= 8; m <<= 1) s += __shfl_xor(s, m, 64);
        red[mi][j] = s;
      }
    if (lid == 0) {
#pragma unroll
      for (int mi = 0; mi < 8; ++mi)
#pragma unroll
        for (int j = 0; j < 4; ++j)
          lS[w * 128 + mi * 16 + grp * 4 + j] = red[mi][j];
    }
    __syncthreads();
#pragma unroll
    for (int mi = 0; mi < 8; ++mi)
#pragma unroll
      for (int j = 0; j < 4; ++j) {
        float tot = red[mi][j] + lS[(w ^ 1) * 128 + mi * 16 + grp * 4 + j];
        rinv[mi][j] = rsqrtf(tot * (1.0f / 128.0f) + 1e-5f) * postscale;
      }
#pragma unroll
    for (int ni = 0; ni < 4; ++ni) {
      float gv = g[(wc & 1) * 64 + ni * 16 + lid];
#pragma unroll
      for (int mi = 0; mi < 8; ++mi)
#pragma unroll
        for (int j = 0; j < 4; ++j)
          acc[mi][ni][j] *= rinv[mi][j] * gv;
    }
  }

#pragma unroll
  for (int mi = 0; mi < 8; ++mi)
#pragma unroll
    for (int ni = 0; ni < 4; ++ni) {
      const int row = tm + wr * 128 + mi * 16 + grp * 4;
      const int col = tn + wc * 64 + ni * 16 + lid;
#pragma unroll
      for (int j = 0; j < 4; ++j) {
        if constexpr (OMODE >= 1)
          ((unsigned short*)Cv)[(size_t)(row + j) * N + col] = f2bf(acc[mi][ni][j]);
        else
          ((float*)Cv)[(size_t)(row + j) * N + col] = acc[mi][ni][j];
      }
    }
}

// ---------- causal flash attention ----------
// 32x32 MFMA, QBLK=32/wave, KVBLK=64, 8 waves/block (256-row q-tiles): one K/V
// staging stream shared by 8 waves (halved per-wave staging + halved HBM refetch).
// Triangle pairing over 8 tiles: jx in 0..3 handles {7-jx, jx} -> 36 steps/block.
// T1 XCD swizzle: the 4 jx blocks of a (b,h) + 8 bh share an XCD's L2.
// Double-buffered K/V; V ds_writes after compute (T14 split). One barrier/step.
// S^T = mfma32(K,Q); O^T = mfma32(V^T, P). Q pre-scaled by hd^-0.5*log2(e).
__global__ __launch_bounds__(512, 2) void attn_kernel(const unsigned short* __restrict__ Q,
                                                      const unsigned short* __restrict__ Kg,
                                                      const unsigned short* __restrict__ Vg,
                                                      unsigned short* __restrict__ O) {
  const int D = 2048, T = 2048;
  __shared__ unsigned short lK[2][64 * 128];   // XOR-swizzled: unit u stores logical u^(row&7)
  __shared__ unsigned short lVT[2][128 * 64];  // V^T, unit u' = u ^ ((d&7)^((d>>3)&7))

  const int tid = threadIdx.x, w = tid >> 6, lane = tid & 63;
  const int lam = lane & 31, H = lane >> 5;
  // XCD-aware bijective swizzle: lin -> (bh, jx); XCD owns 8 bh x 4 jx
  const int lin = blockIdx.x + gridDim.x * blockIdx.y;   // gridDim.x == 4
  const int xcd = lin & 7, idx = lin >> 3;               // idx 0..31
  const int bh = xcd * 8 + (idx >> 2);
  const int jx = idx & 3;
  const int b = bh >> 4, h = bh & 15;
  const size_t base = (size_t)b * T * D + (size_t)h * 128;
  const unsigned short* Qp = Q + base;
  const unsigned short* Kp = Kg + base;
  const unsigned short* Vp = Vg + base;

  fx16 zf;
#pragma unroll
  for (int i = 0; i < 16; ++i) zf[i] = 0.f;

  s16x8 va, vb;   // in-flight V stage regs

  for (int pass = 0; pass < 2; ++pass) {
    const int qt = (pass == 0) ? (7 - jx) : jx;
    const int qb = qt * 256;
    const int q0 = qb + w * 32;
    const int q = q0 + lam;
    const int nsteps = qt * 4 + 4;

    s16x8 qf[8];
    {
      const unsigned short* qrow = Qp + (size_t)q * D + H * 8;
#pragma unroll
      for (int s = 0; s < 8; ++s) qf[s] = *(const s16x8*)(qrow + s * 16);
    }

    fx16 o[4] = {zf, zf, zf, zf};
    float mrun = -1e30f, lrun = 0.f;

    auto vloadV = [&](int kt0) {
      int p = tid >> 4, d8 = tid & 15;
      const unsigned short* vp = Vp + (size_t)(kt0 + p * 2) * D + d8 * 8;
      va = *(const s16x8*)vp;
      vb = *(const s16x8*)(vp + D);
    };
    auto vwriteV = [&](int bsel) {
      int p = tid >> 4, d8 = tid & 15;
#pragma unroll
      for (int j = 0; j < 8; ++j) {
        int d = d8 * 8 + j;
        int up = (p >> 2) ^ j ^ (d8 & 7);     // u ^ f(d), f(d)=(d&7)^((d>>3)&7)
        unsigned int word = (unsigned int)(unsigned short)va[j] |
                            ((unsigned int)(unsigned short)vb[j] << 16);
        *(unsigned int*)&lVT[bsel][d * 64 + up * 8 + (p & 3) * 2] = word;
      }
    };
    auto stageK = [&](int bsel, int kt0) {
#pragma unroll
      for (int i = 0; i < 2; ++i) {
        int c = i * 512 + tid;
        int row = c >> 4, u = c & 15;
        int su = u ^ (row & 7);
        glds16(Kp + (size_t)(kt0 + row) * D + su * 8, &lK[bsel][(i * 512 + w * 64) * 8]);
      }
    };

    vloadV(0);
    stageK(0, 0);
    vwriteV(0);
    __syncthreads();

    for (int s = 0; s < nsteps; ++s) {
      const int kt0 = s << 6;
      const int cur = s & 1, nxt = cur ^ 1;

      if (s + 1 < nsteps) {
        vloadV((s + 1) << 6);
        stageK(nxt, (s + 1) << 6);
      }

      if (kt0 <= q0 + 31) {
        // ---- S^T = mfma32(K, Q)
        fx16 st0 = zf, st1 = zf;
#pragma unroll
        for (int ss = 0; ss < 8; ++ss) {
          int uoff = ((2 * ss + H) ^ (lam & 7)) * 8;
          s16x8 k0 = *(const s16x8*)&lK[cur][lam * 128 + uoff];
          s16x8 k1 = *(const s16x8*)&lK[cur][(32 + lam) * 128 + uoff];
          st0 = mfma32(k0, qf[ss], st0);
          st1 = mfma32(k1, qf[ss], st1);
        }

        // ---- causal mask
        if (kt0 + 63 > q0) {
          const int kb = kt0 + 4 * H;
#pragma unroll
          for (int r = 0; r < 16; ++r) {
            int kv = kb + (r & 3) + 8 * (r >> 2);
            if (kv > q) st0[r] = -1e30f;
            if (kv + 32 > q) st1[r] = -1e30f;
          }
        }

        // ---- online softmax (exp2 domain), T13 defer-max; max3-fusable chains
        float pa = fmaxf(st0[0], st0[1]);
        float pb = fmaxf(st0[2], st0[3]);
#pragma unroll
        for (int r = 4; r < 16; r += 4) {
          pa = fmaxf(fmaxf(pa, st0[r]), st0[r + 1]);
          pb = fmaxf(fmaxf(pb, st0[r + 2]), st0[r + 3]);
        }
#pragma unroll
        for (int r = 0; r < 16; r += 4) {
          pa = fmaxf(fmaxf(pa, st1[r]), st1[r + 1]);
          pb = fmaxf(fmaxf(pb, st1[r + 2]), st1[r + 3]);
        }
        float pmax = fmaxf(pa, pb);
        pmax = fmaxf(pmax, __shfl_xor(pmax, 32, 64));
        if (!__all(pmax <= mrun + 12.f)) {
          float mnew = fmaxf(mrun, pmax);
          float al = exp2f(mrun - mnew);
          mrun = mnew;
          lrun *= al;
#pragma unroll
          for (int r = 0; r < 16; ++r) {
            o[0][r] *= al; o[1][r] *= al; o[2][r] *= al; o[3][r] *= al;
          }
        }
        float lloc = 0.f;
#pragma unroll
        for (int r = 0; r < 16; ++r) { st0[r] = exp2f(st0[r] - mrun); lloc += st0[r]; }
#pragma unroll
        for (int r = 0; r < 16; ++r) { st1[r] = exp2f(st1[r] - mrun); lloc += st1[r]; }
        lrun += lloc;

        // ---- pack P to bf16 pair-words (v_cvt_pk), exchange halves
        unsigned int w0[8], w1[8], w0s[8], w1s[8];
#pragma unroll
        for (int m = 0; m < 8; ++m) {
          w0[m] = cvtpk(st0[2 * m], st0[2 * m + 1]);
          w1[m] = cvtpk(st1[2 * m], st1[2 * m + 1]);
        }
#pragma unroll
        for (int m = 0; m < 8; ++m) {
          w0s[m] = __shfl_xor(w0[m], 32, 64);
          w1s[m] = __shfl_xor(w1[m], 32, 64);
        }

        // ---- PV: O^T += mfma32(V^T_frag, P_frag)
        const bool Hi = (H != 0);
#pragma unroll
        for (int c = 0; c < 4; ++c) {
          union { s16x8 v; unsigned int u[4]; } pbu;
          if (c < 2) {
            const int a = 4 * (c & 1);
            pbu.u[0] = Hi ? w0s[a + 2] : w0[a + 0];
            pbu.u[1] = Hi ? w0s[a + 3] : w0[a + 1];
            pbu.u[2] = Hi ? w0[a + 2] : w0s[a + 0];
            pbu.u[3] = Hi ? w0[a + 3] : w0s[a + 1];
          } else {
            const int a = 4 * (c & 1);
            pbu.u[0] = Hi ? w1s[a + 2] : w1[a + 0];
            pbu.u[1] = Hi ? w1s[a + 3] : w1[a + 1];
            pbu.u[2] = Hi ? w1[a + 2] : w1s[a + 0];
            pbu.u[3] = Hi ? w1[a + 3] : w1s[a + 1];
          }
#pragma unroll
          for (int dt = 0; dt < 4; ++dt) {
            int d = dt * 32 + lam;
            int fd = (lam & 7) ^ ((dt * 4 + (lam >> 3)) & 7);
            s16x8 vf = *(const s16x8*)&lVT[cur][d * 64 + ((2 * c + H) ^ fd) * 8];
            o[dt] = mfma32(vf, pbu.v, o[dt]);
          }
        }
      }

      if (s + 1 < nsteps) vwriteV(nxt);
      __syncthreads();
    }

    // ---- epilogue
    lrun += __shfl_xor(lrun, 32, 64);
    float inv = 1.f / lrun;
    unsigned short* orow = O + base + (size_t)q * D;
#pragma unroll
    for (int dt = 0; dt < 4; ++dt)
#pragma unroll
      for (int rq = 0; rq < 4; ++rq) {
        u32x2 uv;
        uv[0] = cvtpk(o[dt][rq * 4 + 0] * inv, o[dt][rq * 4 + 1] * inv);
        uv[1] = cvtpk(o[dt][rq * 4 + 2] * inv, o[dt][rq * 4 + 3] * inv);
        *(u32x2*)(orow + dt * 32 + rq * 8 + H * 4) = uv;
      }
  }
}

// ---------- launch ----------
extern "C" void kernel_launch(void* const* d_in, const int* in_sizes, int n_in,
                              void* d_out, int out_size, void* d_ws, size_t ws_size,
                              hipStream_t stream) {
  (void)in_sizes; (void)n_in; (void)out_size; (void)ws_size;
  const float* x  = (const float*)d_in[0];
  const float* Wq = (const float*)d_in[1];
  const float* Wk = (const float*)d_in[2];
  const float* Wv = (const float*)d_in[3];
  const float* Wo = (const float*)d_in[4];
  const float* gq = (const float*)d_in[5];
  const float* gk = (const float*)d_in[6];
  float* out = (float*)d_out;

  // workspace layout (bytes): peak 136 MB
  char* W = (char*)d_ws;
  unsigned short* xb    = (unsigned short*)(W);                       // 32 MB  x bf16 (later reused for attn out)
  unsigned short* wslot = (unsigned short*)(W + (size_t)33554432);    //  8 MB  current weight bf16
  unsigned short* Qb    = (unsigned short*)(W + (size_t)41943040);    // 32 MB
  unsigned short* Kb    = (unsigned short*)(W + (size_t)75497472);    // 32 MB
  unsigned short* Vb    = (unsigned short*)(W + (size_t)109051904);   // 32 MB
  unsigned short* AO    = xb;                                         // attn out reuses x region

  const dim3 gg(8, 32);   // N/256, M/256
  const float qscale = (float)(0.08838834764831845 * 1.4426950408889634); // hd^-0.5 * log2(e)

  cvt_kernel<<<4096, 256, 0, stream>>>(x, xb, 16777216);

  cvt_kernel<<<4096, 256, 0, stream>>>(Wq, wslot, 4194304);
  gemm256<2><<<gg, 512, 0, stream>>>(xb, wslot, Qb, gq, qscale, 8192, 2048, 2048);
  cvt_kernel<<<4096, 256, 0, stream>>>(Wk, wslot, 4194304);
  gemm256<2><<<gg, 512, 0, stream>>>(xb, wslot, Kb, gk, 1.0f, 8192, 2048, 2048);
  cvt_kernel<<<4096, 256, 0, stream>>>(Wv, wslot, 4194304);
  gemm256<1><<<gg, 512, 0, stream>>>(xb, wslot, Vb, gq, 1.0f, 8192, 2048, 2048);

  attn_kernel<<<dim3(4, 64), 512, 0, stream>>>(Qb, Kb, Vb, AO);

  cvt_kernel<<<4096, 256, 0, stream>>>(Wo, wslot, 4194304);
  gemm256<0><<<gg, 512, 0, stream>>>(AO, wslot, out, gq, 1.0f, 8192, 2048, 2048);
}

// Round 8
// 419.242 us; speedup vs baseline: 1.6266x; 1.0224x over previous
//
#include <hip/hip_runtime.h>

// ---------- types ----------
typedef short  s16x8 __attribute__((ext_vector_type(8)));
typedef __bf16 bf16x8 __attribute__((ext_vector_type(8)));
typedef float  fx4   __attribute__((ext_vector_type(4)));
typedef float  fx16  __attribute__((ext_vector_type(16)));
typedef unsigned short u16x4 __attribute__((ext_vector_type(4)));
typedef unsigned int   u32x2 __attribute__((ext_vector_type(2)));
typedef unsigned int   u32x4 __attribute__((ext_vector_type(4)));

__device__ __forceinline__ fx4 mfma_bf16(s16x8 a, s16x8 b, fx4 c) {
  return __builtin_amdgcn_mfma_f32_16x16x32_bf16(
      __builtin_bit_cast(bf16x8, a), __builtin_bit_cast(bf16x8, b), c, 0, 0, 0);
}

__device__ __forceinline__ fx16 mfma32(s16x8 a, s16x8 b, fx16 c) {
  return __builtin_amdgcn_mfma_f32_32x32x16_bf16(
      __builtin_bit_cast(bf16x8, a), __builtin_bit_cast(bf16x8, b), c, 0, 0, 0);
}

__device__ __forceinline__ unsigned short f2bf(float f) {
  unsigned int u = __float_as_uint(f);
  u += 0x7fffu + ((u >> 16) & 1u);   // RNE
  return (unsigned short)(u >> 16);
}

__device__ __forceinline__ float bf2f(unsigned int bits16) {
  return __uint_as_float(bits16 << 16);
}

// packed f32x2 -> bf16x2 (RNE), T12 primitive (no builtin on gfx950)
__device__ __forceinline__ unsigned int cvtpk(float lo, float hi) {
  unsigned int r;
  asm volatile("v_cvt_pk_bf16_f32 %0, %1, %2" : "=v"(r) : "v"(lo), "v"(hi));
  return r;
}

// global -> LDS direct copy, 16B per lane; LDS dest = wave-uniform base + lane*16
__device__ __forceinline__ void glds16(const void* g, void* l) {
  __builtin_amdgcn_global_load_lds(
      (__attribute__((address_space(1))) unsigned int*)g,
      (__attribute__((address_space(3))) unsigned int*)l, 16, 0, 0);
}

// ---------- fp32 -> bf16 conversion ----------
__global__ __launch_bounds__(256) void cvt_kernel(const float* __restrict__ src,
                                                  unsigned short* __restrict__ dst, int n) {
  int nv = n >> 2;
  for (int i = blockIdx.x * blockDim.x + threadIdx.x; i < nv; i += gridDim.x * blockDim.x) {
    fx4 v = ((const fx4*)src)[i];
    u16x4 o;
#pragma unroll
    for (int j = 0; j < 4; ++j) o[j] = f2bf(v[j]);
    ((u16x4*)dst)[i] = o;
  }
}

// ---------- GEMM: C[M,N] = A[M,K] * B[N,K]^T ----------
// 256x256 tile, BK=64, 8 waves (2m x 4n), dbuf LDS 128 KiB, XOR-swizzled units.
// 4-phase cadence, THINNED to 3 barriers/tile (r7): lockstep removed so one
// wave's ds_reads overlap another's MFMAs.
//   topBAR: buf cur visible (after prev tile's vmcnt(6))
//   p0: bfr(8)+af0(4) reads; stageA(nxt,kt+1,A13); MFMA0
//   BAR-A   (all p0 reads retired -> B region of cur may be overwritten)
//   p1: af1; stageB(cur,kt+2,B01); MFMA1
//   BAR-B   (af1 reads retired -> A{0,2} of cur may be overwritten)
//   p2: af2; stageB(cur,kt+2,B23); MFMA2
//   p3: af3; stageA(cur,kt+2,A02); MFMA3; vmcnt(6)  [FIFO: drains kt+1's 8]
//   trailing BAR = next tile's topBAR.
// vmcnt never 0 mid-loop (T4). T1 XCD swizzle (gridDim.x==8, gridDim.y%8==0).
// OMODE: 0 = f32 out, 1 = bf16 out, 2 = bf16 + per-head RMSNorm (head_dim=128)
template <int OMODE>
__global__ __launch_bounds__(512, 2) void gemm256(const unsigned short* __restrict__ A,
                                                  const unsigned short* __restrict__ B,
                                                  void* __restrict__ Cv,
                                                  const float* __restrict__ g,
                                                  float postscale,
                                                  int M, int N, int K) {
  __shared__ unsigned short lA[2][256 * 64];
  __shared__ unsigned short lB[2][256 * 64];
  const int tid = threadIdx.x, w = tid >> 6, lane = tid & 63;
  const int lid = lane & 15, grp = lane >> 4;
  const int wr = w >> 2, wc = w & 3;
  // T1 XCD-aware bijective swizzle (dispatch id -> tile)
  const int lin = blockIdx.x + gridDim.x * blockIdx.y;
  const int xcd = lin & 7, idx = lin >> 3;
  const int bx = idx & 7;                              // gridDim.x == 8
  const int by = xcd * (gridDim.y >> 3) + (idx >> 3);
  const int tm = by * 256, tn = bx * 256;

  auto stageA = [&](int buf, int kt, int ia, int ib) {
    const int k0 = kt * 64;
#pragma unroll
    for (int t = 0; t < 2; ++t) {
      int i = t ? ib : ia;
      int c = i * 512 + tid;
      int row = c >> 3, u = c & 7;
      int su = u ^ (row & 7);
      glds16(A + (size_t)(tm + row) * K + k0 + su * 8, &lA[buf][(i * 512 + w * 64) * 8]);
    }
  };
  auto stageB = [&](int buf, int kt, int ia, int ib) {
    const int k0 = kt * 64;
#pragma unroll
    for (int t = 0; t < 2; ++t) {
      int i = t ? ib : ia;
      int c = i * 512 + tid;
      int row = c >> 3, u = c & 7;
      int su = u ^ (row & 7);
      glds16(B + (size_t)(tn + row) * K + k0 + su * 8, &lB[buf][(i * 512 + w * 64) * 8]);
    }
  };

  fx4 acc[8][4];
#pragma unroll
  for (int i = 0; i < 8; ++i)
#pragma unroll
    for (int j = 0; j < 4; ++j) acc[i][j] = fx4{0.f, 0.f, 0.f, 0.f};

  // prologue: tile0 full -> slot0; tile1 B + A{0,2} -> slot1 (A{1,3} issued at kt0.p0)
  stageA(0, 0, 0, 1); stageA(0, 0, 2, 3);
  stageB(0, 0, 0, 1); stageB(0, 0, 2, 3);
  stageB(1, 1, 0, 1); stageB(1, 1, 2, 3);
  stageA(1, 1, 0, 2);
  asm volatile("s_waitcnt vmcnt(6)" ::: "memory");   // tile0's 8 landed
  __builtin_amdgcn_s_barrier();
  __builtin_amdgcn_sched_barrier(0);

#define BARX { __builtin_amdgcn_s_barrier(); __builtin_amdgcn_sched_barrier(0); }
#define LDAF(P)                                                               \
  s16x8 af##P[2][2];                                                          \
  _Pragma("unroll") for (int mi = 0; mi < 2; ++mi)                            \
  _Pragma("unroll") for (int ks = 0; ks < 2; ++ks) {                          \
    int row = wr * 128 + ((P) * 2 + mi) * 16 + lid;                           \
    int u = (ks * 4 + grp) ^ (row & 7);                                       \
    af##P[mi][ks] = *(const s16x8*)&la[row * 64 + u * 8];                     \
  }
#define MFMAG(P)                                                              \
  __builtin_amdgcn_s_setprio(1);                                              \
  _Pragma("unroll") for (int mi = 0; mi < 2; ++mi)                            \
  _Pragma("unroll") for (int ni = 0; ni < 4; ++ni)                            \
  _Pragma("unroll") for (int ks = 0; ks < 2; ++ks)                            \
    acc[(P) * 2 + mi][ni] =                                                   \
        mfma_bf16(af##P[mi][ks], bfr[ni][ks], acc[(P) * 2 + mi][ni]);         \
  __builtin_amdgcn_s_setprio(0);

  const int NT = K >> 6;
  for (int kt = 0; kt < NT; ++kt) {
    const int cur = kt & 1;
    const unsigned short* la = &lA[cur][0];
    const unsigned short* lb = &lB[cur][0];

    // ---- phase 0: bfr (whole tile's B) + af0; stage A{1,3} of kt+1
    s16x8 bfr[4][2];
#pragma unroll
    for (int ni = 0; ni < 4; ++ni)
#pragma unroll
      for (int ks = 0; ks < 2; ++ks) {
        int row = wc * 64 + ni * 16 + lid;
        int u = (ks * 4 + grp) ^ (row & 7);
        bfr[ni][ks] = *(const s16x8*)&lb[row * 64 + u * 8];
      }
    LDAF(0)
    if (kt + 1 < NT) stageA(cur ^ 1, kt + 1, 1, 3);
    MFMAG(0)
    BARX                                   // BAR-A: p0 reads retired
    // ---- phase 1
    LDAF(1)
    if (kt + 2 < NT) stageB(cur, kt + 2, 0, 1);
    MFMAG(1)
    BARX                                   // BAR-B: af1 reads retired
    // ---- phase 2 (barrier-free into phase 3)
    LDAF(2)
    if (kt + 2 < NT) stageB(cur, kt + 2, 2, 3);
    MFMAG(2)
    // ---- phase 3
    LDAF(3)
    if (kt + 2 < NT) stageA(cur, kt + 2, 0, 2);
    MFMAG(3)
    if (kt + 2 < NT) {
      asm volatile("s_waitcnt vmcnt(6)" ::: "memory");   // kt+1's 8 landed
    } else {
      asm volatile("s_waitcnt vmcnt(0)" ::: "memory");
    }
    BARX                                   // trailing = next tile's top barrier
  }
#undef LDAF
#undef MFMAG
#undef BARX

  float rinv[8][4];
  if constexpr (OMODE == 2) {
    // per-row sum of squares over the 128-col head segment (2 waves: wc pairs)
    float* lS = (float*)&lA[0][0];
    float red[8][4];
#pragma unroll
    for (int mi = 0; mi < 8; ++mi)
#pragma unroll
      for (int j = 0; j < 4; ++j) {
        float s = 0.f;
#pragma unroll
        for (int ni = 0; ni < 4; ++ni) { float v = acc[mi][ni][j]; s += v * v; }
#pragma unroll
        for (int m = 1; m <= 8; m <<= 1) s += __shfl_xor(s, m, 64);
        red[mi][j] = s;
      }
    if (lid == 0) {
#pragma unroll
      for (int mi = 0; mi < 8; ++mi)
#pragma unroll
        for (int j = 0; j < 4; ++j)
          lS[w * 128 + mi * 16 + grp * 4 + j] = red[mi][j];
    }
    __syncthreads();
#pragma unroll
    for (int mi = 0; mi < 8; ++mi)
#pragma unroll
      for (int j = 0; j < 4; ++j) {
        float tot = red[mi][j] + lS[(w ^ 1) * 128 + mi * 16 + grp * 4 + j];
        rinv[mi][j] = rsqrtf(tot * (1.0f / 128.0f) + 1e-5f) * postscale;
      }
#pragma unroll
    for (int ni = 0; ni < 4; ++ni) {
      float gv = g[(wc & 1) * 64 + ni * 16 + lid];
#pragma unroll
      for (int mi = 0; mi < 8; ++mi)
#pragma unroll
        for (int j = 0; j < 4; ++j)
          acc[mi][ni][j] *= rinv[mi][j] * gv;
    }
  }

#pragma unroll
  for (int mi = 0; mi < 8; ++mi)
#pragma unroll
    for (int ni = 0; ni < 4; ++ni) {
      const int row = tm + wr * 128 + mi * 16 + grp * 4;
      const int col = tn + wc * 64 + ni * 16 + lid;
#pragma unroll
      for (int j = 0; j < 4; ++j) {
        if constexpr (OMODE >= 1)
          ((unsigned short*)Cv)[(size_t)(row + j) * N + col] = f2bf(acc[mi][ni][j]);
        else
          ((float*)Cv)[(size_t)(row + j) * N + col] = acc[mi][ni][j];
      }
    }
}

// ---------- causal flash attention ----------
// 32x32 MFMA, QBLK=32/wave, KVBLK=64, 8 waves/block (256-row q-tiles): one K/V
// staging stream shared by 8 waves (halved per-wave staging + halved HBM refetch).
// Triangle pairing over 8 tiles: jx in 0..3 handles {7-jx, jx} -> 36 steps/block.
// T1 XCD swizzle: the 4 jx blocks of a (b,h) + 8 bh share an XCD's L2.
// Double-buffered K/V; V ds_writes after compute (T14 split). One barrier/step.
// S^T = mfma32(K,Q); O^T = mfma32(V^T, P). Q pre-scaled by hd^-0.5*log2(e).
__global__ __launch_bounds__(512, 2) void attn_kernel(const unsigned short* __restrict__ Q,
                                                      const unsigned short* __restrict__ Kg,
                                                      const unsigned short* __restrict__ Vg,
                                                      unsigned short* __restrict__ O) {
  const int D = 2048, T = 2048;
  __shared__ unsigned short lK[2][64 * 128];   // XOR-swizzled: unit u stores logical u^(row&7)
  __shared__ unsigned short lVT[2][128 * 64];  // V^T, unit u' = u ^ ((d&7)^((d>>3)&7))

  const int tid = threadIdx.x, w = tid >> 6, lane = tid & 63;
  const int lam = lane & 31, H = lane >> 5;
  // XCD-aware bijective swizzle: lin -> (bh, jx); XCD owns 8 bh x 4 jx
  const int lin = blockIdx.x + gridDim.x * blockIdx.y;   // gridDim.x == 4
  const int xcd = lin & 7, idx = lin >> 3;               // idx 0..31
  const int bh = xcd * 8 + (idx >> 2);
  const int jx = idx & 3;
  const int b = bh >> 4, h = bh & 15;
  const size_t base = (size_t)b * T * D + (size_t)h * 128;
  const unsigned short* Qp = Q + base;
  const unsigned short* Kp = Kg + base;
  const unsigned short* Vp = Vg + base;

  fx16 zf;
#pragma unroll
  for (int i = 0; i < 16; ++i) zf[i] = 0.f;

  s16x8 va, vb;   // in-flight V stage regs

  for (int pass = 0; pass < 2; ++pass) {
    const int qt = (pass == 0) ? (7 - jx) : jx;
    const int qb = qt * 256;
    const int q0 = qb + w * 32;
    const int q = q0 + lam;
    const int nsteps = qt * 4 + 4;

    s16x8 qf[8];
    {
      const unsigned short* qrow = Qp + (size_t)q * D + H * 8;
#pragma unroll
      for (int s = 0; s < 8; ++s) qf[s] = *(const s16x8*)(qrow + s * 16);
    }

    fx16 o[4] = {zf, zf, zf, zf};
    float mrun = -1e30f, lrun = 0.f;

    auto vloadV = [&](int kt0) {
      int p = tid >> 4, d8 = tid & 15;
      const unsigned short* vp = Vp + (size_t)(kt0 + p * 2) * D + d8 * 8;
      va = *(const s16x8*)vp;
      vb = *(const s16x8*)(vp + D);
    };
    auto vwriteV = [&](int bsel) {
      int p = tid >> 4, d8 = tid & 15;
#pragma unroll
      for (int j = 0; j < 8; ++j) {
        int d = d8 * 8 + j;
        int up = (p >> 2) ^ j ^ (d8 & 7);     // u ^ f(d), f(d)=(d&7)^((d>>3)&7)
        unsigned int word = (unsigned int)(unsigned short)va[j] |
                            ((unsigned int)(unsigned short)vb[j] << 16);
        *(unsigned int*)&lVT[bsel][d * 64 + up * 8 + (p & 3) * 2] = word;
      }
    };
    auto stageK = [&](int bsel, int kt0) {
#pragma unroll
      for (int i = 0; i < 2; ++i) {
        int c = i * 512 + tid;
        int row = c >> 4, u = c & 15;
        int su = u ^ (row & 7);
        glds16(Kp + (size_t)(kt0 + row) * D + su * 8, &lK[bsel][(i * 512 + w * 64) * 8]);
      }
    };

    vloadV(0);
    stageK(0, 0);
    vwriteV(0);
    __syncthreads();

    for (int s = 0; s < nsteps; ++s) {
      const int kt0 = s << 6;
      const int cur = s & 1, nxt = cur ^ 1;

      if (s + 1 < nsteps) {
        vloadV((s + 1) << 6);
        stageK(nxt, (s + 1) << 6);
      }

      if (kt0 <= q0 + 31) {
        // ---- S^T = mfma32(K, Q)
        fx16 st0 = zf, st1 = zf;
#pragma unroll
        for (int ss = 0; ss < 8; ++ss) {
          int uoff = ((2 * ss + H) ^ (lam & 7)) * 8;
          s16x8 k0 = *(const s16x8*)&lK[cur][lam * 128 + uoff];
          s16x8 k1 = *(const s16x8*)&lK[cur][(32 + lam) * 128 + uoff];
          st0 = mfma32(k0, qf[ss], st0);
          st1 = mfma32(k1, qf[ss], st1);
        }

        // ---- causal mask
        if (kt0 + 63 > q0) {
          const int kb = kt0 + 4 * H;
#pragma unroll
          for (int r = 0; r < 16; ++r) {
            int kv = kb + (r & 3) + 8 * (r >> 2);
            if (kv > q) st0[r] = -1e30f;
            if (kv + 32 > q) st1[r] = -1e30f;
          }
        }

        // ---- online softmax (exp2 domain), T13 defer-max; max3-fusable chains
        float pa = fmaxf(st0[0], st0[1]);
        float pb = fmaxf(st0[2], st0[3]);
#pragma unroll
        for (int r = 4; r < 16; r += 4) {
          pa = fmaxf(fmaxf(pa, st0[r]), st0[r + 1]);
          pb = fmaxf(fmaxf(pb, st0[r + 2]), st0[r + 3]);
        }
#pragma unroll
        for (int r = 0; r < 16; r += 4) {
          pa = fmaxf(fmaxf(pa, st1[r]), st1[r + 1]);
          pb = fmaxf(fmaxf(pb, st1[r + 2]), st1[r + 3]);
        }
        float pmax = fmaxf(pa, pb);
        pmax = fmaxf(pmax, __shfl_xor(pmax, 32, 64));
        if (!__all(pmax <= mrun + 12.f)) {
          float mnew = fmaxf(mrun, pmax);
          float al = exp2f(mrun - mnew);
          mrun = mnew;
          lrun *= al;
#pragma unroll
          for (int r = 0; r < 16; ++r) {
            o[0][r] *= al; o[1][r] *= al; o[2][r] *= al; o[3][r] *= al;
          }
        }
        float lloc = 0.f;
#pragma unroll
        for (int r = 0; r < 16; ++r) { st0[r] = exp2f(st0[r] - mrun); lloc += st0[r]; }
#pragma unroll
        for (int r = 0; r < 16; ++r) { st1[r] = exp2f(st1[r] - mrun); lloc += st1[r]; }
        lrun += lloc;

        // ---- pack P to bf16 pair-words (v_cvt_pk), exchange halves
        unsigned int w0[8], w1[8], w0s[8], w1s[8];
#pragma unroll
        for (int m = 0; m < 8; ++m) {
          w0[m] = cvtpk(st0[2 * m], st0[2 * m + 1]);
          w1[m] = cvtpk(st1[2 * m], st1[2 * m + 1]);
        }
#pragma unroll
        for (int m = 0; m < 8; ++m) {
          w0s[m] = __shfl_xor(w0[m], 32, 64);
          w1s[m] = __shfl_xor(w1[m], 32, 64);
        }

        // ---- PV: O^T += mfma32(V^T_frag, P_frag)
        const bool Hi = (H != 0);
#pragma unroll
        for (int c = 0; c < 4; ++c) {
          union { s16x8 v; unsigned int u[4]; } pbu;
          if (c < 2) {
            const int a = 4 * (c & 1);
            pbu.u[0] = Hi ? w0s[a + 2] : w0[a + 0];
            pbu.u[1] = Hi ? w0s[a + 3] : w0[a + 1];
            pbu.u[2] = Hi ? w0[a + 2] : w0s[a + 0];
            pbu.u[3] = Hi ? w0[a + 3] : w0s[a + 1];
          } else {
            const int a = 4 * (c & 1);
            pbu.u[0] = Hi ? w1s[a + 2] : w1[a + 0];
            pbu.u[1] = Hi ? w1s[a + 3] : w1[a + 1];
            pbu.u[2] = Hi ? w1[a + 2] : w1s[a + 0];
            pbu.u[3] = Hi ? w1[a + 3] : w1s[a + 1];
          }
#pragma unroll
          for (int dt = 0; dt < 4; ++dt) {
            int d = dt * 32 + lam;
            int fd = (lam & 7) ^ ((dt * 4 + (lam >> 3)) & 7);
            s16x8 vf = *(const s16x8*)&lVT[cur][d * 64 + ((2 * c + H) ^ fd) * 8];
            o[dt] = mfma32(vf, pbu.v, o[dt]);
          }
        }
      }

      if (s + 1 < nsteps) vwriteV(nxt);
      __syncthreads();
    }

    // ---- epilogue
    lrun += __shfl_xor(lrun, 32, 64);
    float inv = 1.f / lrun;
    unsigned short* orow = O + base + (size_t)q * D;
#pragma unroll
    for (int dt = 0; dt < 4; ++dt)
#pragma unroll
      for (int rq = 0; rq < 4; ++rq) {
        u32x2 uv;
        uv[0] = cvtpk(o[dt][rq * 4 + 0] * inv, o[dt][rq * 4 + 1] * inv);
        uv[1] = cvtpk(o[dt][rq * 4 + 2] * inv, o[dt][rq * 4 + 3] * inv);
        *(u32x2*)(orow + dt * 32 + rq * 8 + H * 4) = uv;
      }
  }
}

// ---------- launch ----------
extern "C" void kernel_launch(void* const* d_in, const int* in_sizes, int n_in,
                              void* d_out, int out_size, void* d_ws, size_t ws_size,
                              hipStream_t stream) {
  (void)in_sizes; (void)n_in; (void)out_size; (void)ws_size;
  const float* x  = (const float*)d_in[0];
  const float* Wq = (const float*)d_in[1];
  const float* Wk = (const float*)d_in[2];
  const float* Wv = (const float*)d_in[3];
  const float* Wo = (const float*)d_in[4];
  const float* gq = (const float*)d_in[5];
  const float* gk = (const float*)d_in[6];
  float* out = (float*)d_out;

  // workspace layout (bytes): peak 136 MB
  char* W = (char*)d_ws;
  unsigned short* xb    = (unsigned short*)(W);                       // 32 MB  x bf16 (later reused for attn out)
  unsigned short* wslot = (unsigned short*)(W + (size_t)33554432);    //  8 MB  current weight bf16
  unsigned short* Qb    = (unsigned short*)(W + (size_t)41943040);    // 32 MB
  unsigned short* Kb    = (unsigned short*)(W + (size_t)75497472);    // 32 MB
  unsigned short* Vb    = (unsigned short*)(W + (size_t)109051904);   // 32 MB
  unsigned short* AO    = xb;                                         // attn out reuses x region

  const dim3 gg(8, 32);   // N/256, M/256
  const float qscale = (float)(0.08838834764831845 * 1.4426950408889634); // hd^-0.5 * log2(e)

  cvt_kernel<<<4096, 256, 0, stream>>>(x, xb, 16777216);

  cvt_kernel<<<4096, 256, 0, stream>>>(Wq, wslot, 4194304);
  gemm256<2><<<gg, 512, 0, stream>>>(xb, wslot, Qb, gq, qscale, 8192, 2048, 2048);
  cvt_kernel<<<4096, 256, 0, stream>>>(Wk, wslot, 4194304);
  gemm256<2><<<gg, 512, 0, stream>>>(xb, wslot, Kb, gk, 1.0f, 8192, 2048, 2048);
  cvt_kernel<<<4096, 256, 0, stream>>>(Wv, wslot, 4194304);
  gemm256<1><<<gg, 512, 0, stream>>>(xb, wslot, Vb, gq, 1.0f, 8192, 2048, 2048);

  attn_kernel<<<dim3(4, 64), 512, 0, stream>>>(Qb, Kb, Vb, AO);

  cvt_kernel<<<4096, 256, 0, stream>>>(Wo, wslot, 4194304);
  gemm256<0><<<gg, 512, 0, stream>>>(AO, wslot, out, gq, 1.0f, 8192, 2048, 2048);
}